// Round 1
// baseline (2158.532 us; speedup 1.0000x reference)
//
#include <hip/hip_runtime.h>
#include <cstdint>
#include <cmath>

#define N_HEADS 8
#define DH      64
#define SQ_     2048
#define SKV_    1024
#define DE      512

// ---------------------------------------------------------------------------
// Wave (64-lane) reductions
// ---------------------------------------------------------------------------
__device__ __forceinline__ float wredmax(float v) {
#pragma unroll
  for (int o = 32; o > 0; o >>= 1) v = fmaxf(v, __shfl_xor(v, o));
  return v;
}
__device__ __forceinline__ float wredsum(float v) {
#pragma unroll
  for (int o = 32; o > 0; o >>= 1) v += __shfl_xor(v, o);
  return v;
}
__device__ __forceinline__ int wredsumi(int v) {
#pragma unroll
  for (int o = 32; o > 0; o >>= 1) v += __shfl_xor(v, o);
  return v;
}

// ---------------------------------------------------------------------------
// C[M,N] = A[M,K] @ W[N,K]^T + bias[N]     (all fp32, row-major)
// 128x128 tile, BK=8, 256 threads, 8x8 per-thread tile.
// ---------------------------------------------------------------------------
__global__ __launch_bounds__(256)
void gemm_bias_f32(const float* __restrict__ A, const float* __restrict__ W,
                   const float* __restrict__ bias, float* __restrict__ C,
                   int M, int N, int K) {
  __shared__ float As[8][132];   // [k][m], padded: 132*4B = 528B rows (16B aligned)
  __shared__ float Ws[8][132];   // [k][n]
  const int t  = threadIdx.x;
  const int tx = t & 15;         // 16 col groups
  const int ty = t >> 4;         // 16 row groups
  const int m0 = blockIdx.y * 128;
  const int n0 = blockIdx.x * 128;

  const int lr = t >> 1;         // 0..127 : row within tile for staging
  const int lc = (t & 1) * 4;    // 0 or 4 : k offset for staging

  const float* Ap = A + (size_t)(m0 + lr) * K + lc;
  const float* Wp = W + (size_t)(n0 + lr) * K + lc;

  float acc[8][8] = {};

  for (int k0 = 0; k0 < K; k0 += 8) {
    float4 av = *(const float4*)(Ap + k0);
    float4 wv = *(const float4*)(Wp + k0);
    As[lc + 0][lr] = av.x; As[lc + 1][lr] = av.y;
    As[lc + 2][lr] = av.z; As[lc + 3][lr] = av.w;
    Ws[lc + 0][lr] = wv.x; Ws[lc + 1][lr] = wv.y;
    Ws[lc + 2][lr] = wv.z; Ws[lc + 3][lr] = wv.w;
    __syncthreads();
#pragma unroll
    for (int kk = 0; kk < 8; ++kk) {
      float a[8], b[8];
      *(float4*)&a[0] = *(const float4*)&As[kk][ty * 8];
      *(float4*)&a[4] = *(const float4*)&As[kk][ty * 8 + 4];
      *(float4*)&b[0] = *(const float4*)&Ws[kk][tx * 8];
      *(float4*)&b[4] = *(const float4*)&Ws[kk][tx * 8 + 4];
#pragma unroll
      for (int i = 0; i < 8; ++i)
#pragma unroll
        for (int j = 0; j < 8; ++j) acc[i][j] = fmaf(a[i], b[j], acc[i][j]);
    }
    __syncthreads();
  }

  float4 b0 = *(const float4*)(bias + n0 + tx * 8);
  float4 b1 = *(const float4*)(bias + n0 + tx * 8 + 4);
#pragma unroll
  for (int i = 0; i < 8; ++i) {
    const int m = m0 + ty * 8 + i;
    float* Crow = C + (size_t)m * N + n0 + tx * 8;
    float4 o0, o1;
    o0.x = acc[i][0] + b0.x; o0.y = acc[i][1] + b0.y;
    o0.z = acc[i][2] + b0.z; o0.w = acc[i][3] + b0.w;
    o1.x = acc[i][4] + b1.x; o1.y = acc[i][5] + b1.y;
    o1.z = acc[i][6] + b1.z; o1.w = acc[i][7] + b1.w;
    *(float4*)Crow = o0;
    *(float4*)(Crow + 4) = o1;
  }
}

// ---------------------------------------------------------------------------
// Fused attention: per block = (b, h, 16 q-rows).
// Computes S = qK^T*scale (fp32), softmax, entropy->top_k, exact k-th-largest
// threshold (duplicate-aware, matching sorted_w[top_k-1] semantics), sparse
// renormalized PV. Output layout [b, q, h*64+d] (ready for O-projection GEMM).
// ---------------------------------------------------------------------------
__global__ __launch_bounds__(256)
void attn_sparse_kernel(const float* __restrict__ qb, const float* __restrict__ kb,
                        const float* __restrict__ vb, float* __restrict__ ob) {
  __shared__ float Qs[16][64];
  __shared__ float S[16][1024];

  const int bid = blockIdx.x;
  const int qt = bid & 127;          // SQ/16 = 128 q-tiles
  const int h  = (bid >> 7) & 7;
  const int b  = bid >> 10;
  const int t  = threadIdx.x;
  const int w  = t >> 6;             // wave id 0..3
  const int l  = t & 63;             // lane

  // Load 16x64 Q tile (coalesced float4)
  {
    const int r = t >> 4, d4 = (t & 15) << 2;
    *(float4*)&Qs[r][d4] =
        *(const float4*)(qb + (size_t)(b * SQ_ + qt * 16 + r) * DE + h * DH + d4);
  }
  __syncthreads();

  const int r0 = w * 4;   // each wave owns 4 q-rows
  const float scale = 0.125f;  // 1/sqrt(64)

  // ---- S = Q K^T * scale : lane <-> kv position, 4 rows per wave
  for (int kv0 = 0; kv0 < SKV_; kv0 += 64) {
    const int kv = kv0 + l;
    const float* krow = kb + (size_t)(b * SKV_ + kv) * DE + h * DH;
    float a0 = 0.f, a1 = 0.f, a2 = 0.f, a3 = 0.f;
#pragma unroll
    for (int d0 = 0; d0 < DH; d0 += 4) {
      float4 kf = *(const float4*)(krow + d0);
      float4 q0 = *(const float4*)&Qs[r0 + 0][d0];
      float4 q1 = *(const float4*)&Qs[r0 + 1][d0];
      float4 q2 = *(const float4*)&Qs[r0 + 2][d0];
      float4 q3 = *(const float4*)&Qs[r0 + 3][d0];
      a0 = fmaf(q0.x, kf.x, fmaf(q0.y, kf.y, fmaf(q0.z, kf.z, fmaf(q0.w, kf.w, a0))));
      a1 = fmaf(q1.x, kf.x, fmaf(q1.y, kf.y, fmaf(q1.z, kf.z, fmaf(q1.w, kf.w, a1))));
      a2 = fmaf(q2.x, kf.x, fmaf(q2.y, kf.y, fmaf(q2.z, kf.z, fmaf(q2.w, kf.w, a2))));
      a3 = fmaf(q3.x, kf.x, fmaf(q3.y, kf.y, fmaf(q3.z, kf.z, fmaf(q3.w, kf.w, a3))));
    }
    S[r0 + 0][kv] = a0 * scale;
    S[r0 + 1][kv] = a1 * scale;
    S[r0 + 2][kv] = a2 * scale;
    S[r0 + 3][kv] = a3 * scale;
  }
  __syncthreads();

  // ---- per-row: softmax -> entropy -> top_k -> threshold -> sparse PV
  for (int i = 0; i < 4; ++i) {
    const int r = r0 + i;
    float* Sr = S[r];

    // pass 1: row max
    float lm = -INFINITY;
#pragma unroll
    for (int j = 0; j < 16; ++j) lm = fmaxf(lm, Sr[l + 64 * j]);
    const float m = wredmax(lm);

    // pass 2: exp + Z (store p in place)
    float lz = 0.f;
#pragma unroll
    for (int j = 0; j < 16; ++j) {
      float p = expf(Sr[l + 64 * j] - m);
      Sr[l + 64 * j] = p;
      lz += p;
    }
    const float Z = wredsum(lz);

    // pass 3: normalize to w, entropy = -sum w*log(w+1e-8)
    float le = 0.f;
#pragma unroll
    for (int j = 0; j < 16; ++j) {
      float wv = Sr[l + 64 * j] / Z;
      Sr[l + 64 * j] = wv;
      le += wv * logf(wv + 1e-8f);
    }
    const float E = -wredsum(le);

    int tk = (int)(32.0f * (1.0f - E));   // trunc toward zero, like .astype(int32)
    tk = tk < 1 ? 1 : (tk > 32 ? 32 : tk);

    // exact tk-th largest of w (duplicate-aware iterative extraction)
    float cur = INFINITY, thr = 0.f;
    int remaining = tk;
    while (true) {
      float lmx = -INFINITY;
#pragma unroll
      for (int j = 0; j < 16; ++j) {
        float wv = Sr[l + 64 * j];
        if (wv < cur) lmx = fmaxf(lmx, wv);
      }
      const float m2 = wredmax(lmx);
      int lcnt = 0;
#pragma unroll
      for (int j = 0; j < 16; ++j) lcnt += (Sr[l + 64 * j] == m2) ? 1 : 0;
      const int c = wredsumi(lcnt);
      if (c >= remaining) { thr = m2; break; }
      remaining -= c;
      cur = m2;
    }

    // sparse PV: lane <-> head dim; iterate selected kv via ballot
    float accv = 0.f, psel = 0.f;
    const float* vB = vb + (size_t)(b * SKV_) * DE + h * DH + l;
    for (int j = 0; j < 16; ++j) {
      unsigned long long msk = __ballot(Sr[l + 64 * j] >= thr);
      while (msk) {
        const int bit = __builtin_ctzll(msk);
        msk &= msk - 1;
        const int kv = 64 * j + bit;
        const float wv = Sr[kv];            // LDS broadcast
        psel += wv;
        accv = fmaf(wv, vB[(size_t)kv * DE], accv);
      }
    }
    const float od = accv / (psel + 1e-8f);
    ob[(size_t)(b * SQ_ + qt * 16 + r) * DE + h * DH + l] = od;
  }
}

// ---------------------------------------------------------------------------
extern "C" void kernel_launch(void* const* d_in, const int* in_sizes, int n_in,
                              void* d_out, int out_size, void* d_ws, size_t ws_size,
                              hipStream_t stream) {
  const float* x  = (const float*)d_in[0];
  const float* y  = (const float*)d_in[1];
  const float* wq = (const float*)d_in[2];
  const float* bq = (const float*)d_in[3];
  const float* wk = (const float*)d_in[4];
  const float* bk = (const float*)d_in[5];
  const float* wv = (const float*)d_in[6];
  const float* bv = (const float*)d_in[7];
  const float* wo = (const float*)d_in[8];
  const float* bo = (const float*)d_in[9];
  float* out = (float*)d_out;

  char* ws = (char*)d_ws;
  float* q  = (float*)(ws);                                   // 16384*512 f32 = 32MB
  float* k  = (float*)(ws + (size_t)33554432);                // 8192*512 f32 = 16MB
  float* v  = (float*)(ws + (size_t)33554432 + 16777216);     // 16MB
  float* ao = (float*)(ws + (size_t)33554432 + 2 * 16777216); // 32MB

  dim3 blk(256);
  // Q = x @ wq^T + bq : [16384,512] x [512,512]
  gemm_bias_f32<<<dim3(4, 128), blk, 0, stream>>>(x, wq, bq, q, 16384, 512, 512);
  // K = y @ wk^T + bk : [8192,768] x [512,768]
  gemm_bias_f32<<<dim3(4, 64), blk, 0, stream>>>(y, wk, bk, k, 8192, 512, 768);
  // V = y @ wv^T + bv
  gemm_bias_f32<<<dim3(4, 64), blk, 0, stream>>>(y, wv, bv, v, 8192, 512, 768);
  // fused sparse attention
  attn_sparse_kernel<<<dim3(8 * N_HEADS * (SQ_ / 16)), blk, 0, stream>>>(q, k, v, ao);
  // out = ao @ wo^T + bo
  gemm_bias_f32<<<dim3(4, 128), blk, 0, stream>>>(ao, wo, bo, out, 16384, 512, 512);
}

// Round 2
// 995.142 us; speedup vs baseline: 2.1691x; 2.1691x over previous
//
#include <hip/hip_runtime.h>
#include <cstdint>
#include <cmath>

#define N_HEADS 8
#define DH      64
#define SQ_     2048
#define SKV_    1024
#define DE      512
#define TQ      16

// ---------------------------------------------------------------------------
// Wave (64-lane) reductions
// ---------------------------------------------------------------------------
__device__ __forceinline__ float wredmax(float v) {
#pragma unroll
  for (int o = 32; o > 0; o >>= 1) v = fmaxf(v, __shfl_xor(v, o));
  return v;
}
__device__ __forceinline__ float wredsum(float v) {
#pragma unroll
  for (int o = 32; o > 0; o >>= 1) v += __shfl_xor(v, o);
  return v;
}

// ---------------------------------------------------------------------------
// C[M,N] = A[M,K] @ W[N,K]^T + bias[N]     (all fp32, row-major)
// 128x128 tile, BK=8, 256 threads, 8x8 per-thread tile. (unchanged from R1)
// ---------------------------------------------------------------------------
__global__ __launch_bounds__(256)
void gemm_bias_f32(const float* __restrict__ A, const float* __restrict__ W,
                   const float* __restrict__ bias, float* __restrict__ C,
                   int M, int N, int K) {
  __shared__ float As[8][132];
  __shared__ float Ws[8][132];
  const int t  = threadIdx.x;
  const int tx = t & 15;
  const int ty = t >> 4;
  const int m0 = blockIdx.y * 128;
  const int n0 = blockIdx.x * 128;

  const int lr = t >> 1;
  const int lc = (t & 1) * 4;

  const float* Ap = A + (size_t)(m0 + lr) * K + lc;
  const float* Wp = W + (size_t)(n0 + lr) * K + lc;

  float acc[8][8] = {};

  for (int k0 = 0; k0 < K; k0 += 8) {
    float4 av = *(const float4*)(Ap + k0);
    float4 wv = *(const float4*)(Wp + k0);
    As[lc + 0][lr] = av.x; As[lc + 1][lr] = av.y;
    As[lc + 2][lr] = av.z; As[lc + 3][lr] = av.w;
    Ws[lc + 0][lr] = wv.x; Ws[lc + 1][lr] = wv.y;
    Ws[lc + 2][lr] = wv.z; Ws[lc + 3][lr] = wv.w;
    __syncthreads();
#pragma unroll
    for (int kk = 0; kk < 8; ++kk) {
      float a[8], b[8];
      *(float4*)&a[0] = *(const float4*)&As[kk][ty * 8];
      *(float4*)&a[4] = *(const float4*)&As[kk][ty * 8 + 4];
      *(float4*)&b[0] = *(const float4*)&Ws[kk][tx * 8];
      *(float4*)&b[4] = *(const float4*)&Ws[kk][tx * 8 + 4];
#pragma unroll
      for (int i = 0; i < 8; ++i)
#pragma unroll
        for (int j = 0; j < 8; ++j) acc[i][j] = fmaf(a[i], b[j], acc[i][j]);
    }
    __syncthreads();
  }

  float4 b0 = *(const float4*)(bias + n0 + tx * 8);
  float4 b1 = *(const float4*)(bias + n0 + tx * 8 + 4);
#pragma unroll
  for (int i = 0; i < 8; ++i) {
    const int m = m0 + ty * 8 + i;
    float* Crow = C + (size_t)m * N + n0 + tx * 8;
    float4 o0, o1;
    o0.x = acc[i][0] + b0.x; o0.y = acc[i][1] + b0.y;
    o0.z = acc[i][2] + b0.z; o0.w = acc[i][3] + b0.w;
    o1.x = acc[i][4] + b1.x; o1.y = acc[i][5] + b1.y;
    o1.z = acc[i][6] + b1.z; o1.w = acc[i][7] + b1.w;
    *(float4*)Crow = o0;
    *(float4*)(Crow + 4) = o1;
  }
}

// ---------------------------------------------------------------------------
// K transpose: k[b, kv, h*64+d] -> kt[(b*8+h)*64 + d][kv]  (per-head [d][kv])
// ---------------------------------------------------------------------------
__global__ __launch_bounds__(256)
void transpose_k(const float* __restrict__ k, float* __restrict__ kt) {
  __shared__ float tile[64][65];
  const int blk = blockIdx.x;        // b*128 + h*16 + kvt
  const int kvt = blk & 15;
  const int h   = (blk >> 4) & 7;
  const int b   = blk >> 7;
  const int t  = threadIdx.x;
  const int r  = t >> 4;             // 0..15
  const int c4 = (t & 15) << 2;      // 0..60

#pragma unroll
  for (int i = 0; i < 4; ++i) {
    const int kvl = r + 16 * i;
    float4 v = *(const float4*)(k + (size_t)(b * SKV_ + kvt * 64 + kvl) * DE + h * DH + c4);
    tile[kvl][c4 + 0] = v.x; tile[kvl][c4 + 1] = v.y;
    tile[kvl][c4 + 2] = v.z; tile[kvl][c4 + 3] = v.w;
  }
  __syncthreads();
#pragma unroll
  for (int i = 0; i < 4; ++i) {
    const int d = r + 16 * i;
    float4 o;
    o.x = tile[c4 + 0][d]; o.y = tile[c4 + 1][d];
    o.z = tile[c4 + 2][d]; o.w = tile[c4 + 3][d];
    *(float4*)(kt + (size_t)((b * 8 + h) * 64 + d) * SKV_ + kvt * 64 + c4) = o;
  }
}

// ---------------------------------------------------------------------------
// Fused sparse attention v2: S fully in registers.
// Block = (b,h,16 q-rows), 4 waves; wave w owns kv quarter [256w,256w+256).
// Lane l, reg c -> kv = 256w + 64c + l. s[q][c]: 64 acc VGPRs.
// Cross-wave row stats via small LDS partials.
// ---------------------------------------------------------------------------
__global__ __launch_bounds__(256, 3)
void attn_sparse_v2(const float* __restrict__ qb, const float* __restrict__ kt,
                    const float* __restrict__ vb, float* __restrict__ ob) {
  __shared__ float Qs[TQ][64];          // 4KB
  __shared__ float pA[TQ][4];           // partial max / extraction max
  __shared__ float pZ[TQ][4];
  __shared__ float pH[TQ][4];
  __shared__ float pC[TQ][4];           // extraction counts (float, exact)
  __shared__ float pS[TQ][4];           // selected-sum partials
  __shared__ float pout[4][TQ][64];     // 16KB PV partials
  __shared__ float scur[TQ];            // slow-path state
  __shared__ float srem[TQ];
  __shared__ int   stk[TQ];

  const int bid = blockIdx.x;
  const int qt = bid & 127;
  const int h  = (bid >> 7) & 7;
  const int b  = bid >> 10;
  const int t  = threadIdx.x;
  const int w  = t >> 6;
  const int l  = t & 63;

  // stage Q tile
  {
    const int r = t >> 4, d4 = (t & 15) << 2;
    *(float4*)&Qs[r][d4] =
        *(const float4*)(qb + (size_t)(b * SQ_ + qt * TQ + r) * DE + h * DH + d4);
  }
  __syncthreads();

  // ---- QK^T into registers (scaled)
  float s[TQ][4] = {};
  const float* kth = kt + (size_t)((b * 8 + h) * 64) * SKV_ + w * 256 + l;
  for (int d0 = 0; d0 < 64; d0 += 4) {
    float kr[4][4];
#pragma unroll
    for (int dd = 0; dd < 4; ++dd)
#pragma unroll
      for (int c = 0; c < 4; ++c)
        kr[dd][c] = kth[(size_t)(d0 + dd) * SKV_ + c * 64];
#pragma unroll
    for (int q = 0; q < TQ; ++q) {
      float4 qv = *(const float4*)&Qs[q][d0];
#pragma unroll
      for (int c = 0; c < 4; ++c)
        s[q][c] = fmaf(qv.w, kr[3][c],
                  fmaf(qv.z, kr[2][c],
                  fmaf(qv.y, kr[1][c],
                  fmaf(qv.x, kr[0][c], s[q][c]))));
    }
  }
  const float scale = 0.125f;
#pragma unroll
  for (int q = 0; q < TQ; ++q)
#pragma unroll
    for (int c = 0; c < 4; ++c) s[q][c] *= scale;

  // ---- row max partials
#pragma unroll
  for (int q = 0; q < TQ; ++q) {
    float lm = fmaxf(fmaxf(s[q][0], s[q][1]), fmaxf(s[q][2], s[q][3]));
    lm = wredmax(lm);
    if (l == 0) pA[q][w] = lm;
  }
  __syncthreads();

  // ---- p = exp(s-m); Z,H partials (H = sum p*(s-m) == sum p*log p)
#pragma unroll
  for (int q = 0; q < TQ; ++q) {
    const float mq = fmaxf(fmaxf(pA[q][0], pA[q][1]), fmaxf(pA[q][2], pA[q][3]));
    float zl = 0.f, hl = 0.f;
#pragma unroll
    for (int c = 0; c < 4; ++c) {
      const float sv = s[q][c] - mq;
      const float p = expf(sv);
      s[q][c] = p;
      zl += p;
      hl = fmaf(p, sv, hl);
    }
    zl = wredsum(zl); hl = wredsum(hl);
    if (l == 0) { pZ[q][w] = zl; pH[q][w] = hl; }
  }
  __syncthreads();

  // ---- tk per row; convert p -> w; extraction pass 1 partial max
#pragma unroll
  for (int q = 0; q < TQ; ++q) {
    const float Zq = (pZ[q][0] + pZ[q][1]) + (pZ[q][2] + pZ[q][3]);
    const float Hq = (pH[q][0] + pH[q][1]) + (pH[q][2] + pH[q][3]);
    const float E = logf(Zq) - Hq / Zq;   // == -sum w log w (eps-free, margin huge)
    int tk = (int)(32.0f * (1.0f - E));
    tk = tk < 1 ? 1 : (tk > 32 ? 32 : tk);
    if (w == 0 && l == 0) stk[q] = tk;
#pragma unroll
    for (int c = 0; c < 4; ++c) s[q][c] = s[q][c] / Zq;   // w values
    float lm = fmaxf(fmaxf(s[q][0], s[q][1]), fmaxf(s[q][2], s[q][3]));
    lm = wredmax(lm);
    if (l == 0) pA[q][w] = lm;
  }
  __syncthreads();

  // ---- extraction pass 1: count values == global max
  float m2r[TQ];
#pragma unroll
  for (int q = 0; q < TQ; ++q) {
    const float m2 = fmaxf(fmaxf(pA[q][0], pA[q][1]), fmaxf(pA[q][2], pA[q][3]));
    m2r[q] = m2;
    float lc = 0.f;
#pragma unroll
    for (int c = 0; c < 4; ++c) lc += (s[q][c] == m2) ? 1.f : 0.f;
    lc = wredsum(lc);
    if (l == 0) pC[q][w] = lc;
  }
  __syncthreads();

  float thr[TQ];
  int pend = 0;
#pragma unroll
  for (int q = 0; q < TQ; ++q) {
    const float cnt = (pC[q][0] + pC[q][1]) + (pC[q][2] + pC[q][3]);
    const int tk = stk[q];
    if (cnt >= (float)tk) {
      thr[q] = m2r[q];
    } else {
      thr[q] = 0.f;
      pend |= (1 << q);
      if (w == 0 && l == 0) { scur[q] = m2r[q]; srem[q] = (float)tk - cnt; }
    }
  }
  __syncthreads();   // srem/scur visible; pA/pC reusable

  // ---- slow path (rare): batched duplicate-aware extraction iterations
  while (pend) {
#pragma unroll
    for (int q = 0; q < TQ; ++q) {
      if (pend & (1 << q)) {
        const float cu = scur[q];
        float lm = -INFINITY;
#pragma unroll
        for (int c = 0; c < 4; ++c) {
          const float wv = s[q][c];
          if (wv < cu) lm = fmaxf(lm, wv);
        }
        lm = wredmax(lm);
        if (l == 0) pA[q][w] = lm;
      }
    }
    __syncthreads();
#pragma unroll
    for (int q = 0; q < TQ; ++q) {
      if (pend & (1 << q)) {
        const float m2 = fmaxf(fmaxf(pA[q][0], pA[q][1]), fmaxf(pA[q][2], pA[q][3]));
        m2r[q] = m2;
        float lc = 0.f;
#pragma unroll
        for (int c = 0; c < 4; ++c) lc += (s[q][c] == m2) ? 1.f : 0.f;
        lc = wredsum(lc);
        if (l == 0) pC[q][w] = lc;
      }
    }
    __syncthreads();
#pragma unroll
    for (int q = 0; q < TQ; ++q) {
      if (pend & (1 << q)) {
        const float cnt = (pC[q][0] + pC[q][1]) + (pC[q][2] + pC[q][3]);
        const float rm = srem[q];
        if (cnt >= rm) {
          thr[q] = m2r[q];
          pend &= ~(1 << q);
        } else {
          if (w == 0 && l == 0) { srem[q] = rm - cnt; scur[q] = m2r[q]; }
        }
      }
    }
    __syncthreads();
  }

  // ---- sparse PV: per-wave partial over its kv quarter, lane <-> head dim
  float acc[TQ] = {};
#pragma unroll
  for (int q = 0; q < TQ; ++q) {
    float ps = 0.f;
#pragma unroll
    for (int c = 0; c < 4; ++c) {
      const bool sel = (s[q][c] >= thr[q]);
      ps += sel ? s[q][c] : 0.f;
      unsigned long long msk = __ballot(sel);
      while (msk) {
        const int bit = __builtin_ctzll(msk);
        msk &= msk - 1;
        const float wv = __shfl(s[q][c], bit);
        const int kv = w * 256 + c * 64 + bit;
        acc[q] = fmaf(wv, vb[(size_t)(b * SKV_ + kv) * DE + h * DH + l], acc[q]);
      }
    }
    ps = wredsum(ps);
    if (l == 0) pS[q][w] = ps;
  }
#pragma unroll
  for (int q = 0; q < TQ; ++q) pout[w][q][l] = acc[q];
  __syncthreads();

  // ---- combine across waves; wave w finalizes rows 4w..4w+3
#pragma unroll
  for (int i = 0; i < 4; ++i) {
    const int q = w * 4 + i;
    const float o = ((pout[0][q][l] + pout[1][q][l]) + (pout[2][q][l] + pout[3][q][l]));
    const float Zs = (pS[q][0] + pS[q][1]) + (pS[q][2] + pS[q][3]);
    ob[(size_t)(b * SQ_ + qt * TQ + q) * DE + h * DH + l] = o / (Zs + 1e-8f);
  }
}

// ---------------------------------------------------------------------------
extern "C" void kernel_launch(void* const* d_in, const int* in_sizes, int n_in,
                              void* d_out, int out_size, void* d_ws, size_t ws_size,
                              hipStream_t stream) {
  const float* x  = (const float*)d_in[0];
  const float* y  = (const float*)d_in[1];
  const float* wq = (const float*)d_in[2];
  const float* bq = (const float*)d_in[3];
  const float* wk = (const float*)d_in[4];
  const float* bk = (const float*)d_in[5];
  const float* wv = (const float*)d_in[6];
  const float* bv = (const float*)d_in[7];
  const float* wo = (const float*)d_in[8];
  const float* bo = (const float*)d_in[9];
  float* out = (float*)d_out;

  char* ws = (char*)d_ws;
  float* q  = (float*)(ws);                         // 32MB
  float* k  = (float*)(ws + (size_t)32 * 1048576);  // 16MB
  float* v  = (float*)(ws + (size_t)48 * 1048576);  // 16MB
  float* ao = (float*)(ws + (size_t)64 * 1048576);  // 32MB
  float* kt = (float*)(ws + (size_t)96 * 1048576);  // 16MB

  dim3 blk(256);
  gemm_bias_f32<<<dim3(4, 128), blk, 0, stream>>>(x, wq, bq, q, 16384, 512, 512);
  gemm_bias_f32<<<dim3(4, 64), blk, 0, stream>>>(y, wk, bk, k, 8192, 512, 768);
  gemm_bias_f32<<<dim3(4, 64), blk, 0, stream>>>(y, wv, bv, v, 8192, 512, 768);
  transpose_k<<<dim3(1024), blk, 0, stream>>>(k, kt);
  attn_sparse_v2<<<dim3(8 * N_HEADS * (SQ_ / TQ)), blk, 0, stream>>>(q, kt, v, ao);
  gemm_bias_f32<<<dim3(4, 128), blk, 0, stream>>>(ao, wo, bo, out, 16384, 512, 512);
}

// Round 3
// 809.255 us; speedup vs baseline: 2.6673x; 1.2297x over previous
//
#include <hip/hip_runtime.h>
#include <cstdint>
#include <cmath>

#define N_HEADS 8
#define DH      64
#define SQ_     2048
#define SKV_    1024
#define DE      512
#define TQ      16

__device__ __forceinline__ float wredmax(float v) {
#pragma unroll
  for (int o = 32; o > 0; o >>= 1) v = fmaxf(v, __shfl_xor(v, o));
  return v;
}
__device__ __forceinline__ float wredsum(float v) {
#pragma unroll
  for (int o = 32; o > 0; o >>= 1) v += __shfl_xor(v, o);
  return v;
}

#define FMA4(d, a, b) \
  d.x = fmaf(a, b.x, d.x); d.y = fmaf(a, b.y, d.y); \
  d.z = fmaf(a, b.z, d.z); d.w = fmaf(a, b.w, d.w)

// ---------------------------------------------------------------------------
// C[M,N] = A[M,K] @ W[N,K]^T + bias[N] (fp32). 128x128 tile, BK=8,
// double-buffered LDS + register prefetch: one barrier per K-step.
// ---------------------------------------------------------------------------
__global__ __launch_bounds__(256)
void gemm_bias_f32(const float* __restrict__ A, const float* __restrict__ W,
                   const float* __restrict__ bias, float* __restrict__ C,
                   int M, int N, int K) {
  __shared__ float As[2][8][132];
  __shared__ float Ws[2][8][132];
  const int t  = threadIdx.x;
  const int tx = t & 15;
  const int ty = t >> 4;
  const int m0 = blockIdx.y * 128;
  const int n0 = blockIdx.x * 128;
  const int lr = t >> 1;
  const int lc = (t & 1) * 4;

  const float* Ap = A + (size_t)(m0 + lr) * K + lc;
  const float* Wp = W + (size_t)(n0 + lr) * K + lc;

  float acc[8][8] = {};

  {
    float4 av = *(const float4*)(Ap);
    float4 wv = *(const float4*)(Wp);
    As[0][lc + 0][lr] = av.x; As[0][lc + 1][lr] = av.y;
    As[0][lc + 2][lr] = av.z; As[0][lc + 3][lr] = av.w;
    Ws[0][lc + 0][lr] = wv.x; Ws[0][lc + 1][lr] = wv.y;
    Ws[0][lc + 2][lr] = wv.z; Ws[0][lc + 3][lr] = wv.w;
  }
  __syncthreads();

  int buf = 0;
  for (int k0 = 8; k0 < K; k0 += 8) {
    float4 av = *(const float4*)(Ap + k0);   // prefetch next tile
    float4 wv = *(const float4*)(Wp + k0);
#pragma unroll
    for (int kk = 0; kk < 8; ++kk) {
      float a[8], b[8];
      *(float4*)&a[0] = *(const float4*)&As[buf][kk][ty * 8];
      *(float4*)&a[4] = *(const float4*)&As[buf][kk][ty * 8 + 4];
      *(float4*)&b[0] = *(const float4*)&Ws[buf][kk][tx * 8];
      *(float4*)&b[4] = *(const float4*)&Ws[buf][kk][tx * 8 + 4];
#pragma unroll
      for (int i = 0; i < 8; ++i)
#pragma unroll
        for (int j = 0; j < 8; ++j) acc[i][j] = fmaf(a[i], b[j], acc[i][j]);
    }
    const int nb = buf ^ 1;
    As[nb][lc + 0][lr] = av.x; As[nb][lc + 1][lr] = av.y;
    As[nb][lc + 2][lr] = av.z; As[nb][lc + 3][lr] = av.w;
    Ws[nb][lc + 0][lr] = wv.x; Ws[nb][lc + 1][lr] = wv.y;
    Ws[nb][lc + 2][lr] = wv.z; Ws[nb][lc + 3][lr] = wv.w;
    __syncthreads();
    buf = nb;
  }
#pragma unroll
  for (int kk = 0; kk < 8; ++kk) {
    float a[8], b[8];
    *(float4*)&a[0] = *(const float4*)&As[buf][kk][ty * 8];
    *(float4*)&a[4] = *(const float4*)&As[buf][kk][ty * 8 + 4];
    *(float4*)&b[0] = *(const float4*)&Ws[buf][kk][tx * 8];
    *(float4*)&b[4] = *(const float4*)&Ws[buf][kk][tx * 8 + 4];
#pragma unroll
    for (int i = 0; i < 8; ++i)
#pragma unroll
      for (int j = 0; j < 8; ++j) acc[i][j] = fmaf(a[i], b[j], acc[i][j]);
  }

  float4 b0 = *(const float4*)(bias + n0 + tx * 8);
  float4 b1 = *(const float4*)(bias + n0 + tx * 8 + 4);
#pragma unroll
  for (int i = 0; i < 8; ++i) {
    const int m = m0 + ty * 8 + i;
    float* Crow = C + (size_t)m * N + n0 + tx * 8;
    float4 o0, o1;
    o0.x = acc[i][0] + b0.x; o0.y = acc[i][1] + b0.y;
    o0.z = acc[i][2] + b0.z; o0.w = acc[i][3] + b0.w;
    o1.x = acc[i][4] + b1.x; o1.y = acc[i][5] + b1.y;
    o1.z = acc[i][6] + b1.z; o1.w = acc[i][7] + b1.w;
    *(float4*)Crow = o0;
    *(float4*)(Crow + 4) = o1;
  }
}

// ---------------------------------------------------------------------------
// K transpose: k[b, kv, h*64+d] -> kt[(b*8+h)*64 + d][kv]
// ---------------------------------------------------------------------------
__global__ __launch_bounds__(256)
void transpose_k(const float* __restrict__ k, float* __restrict__ kt) {
  __shared__ float tile[64][65];
  const int blk = blockIdx.x;
  const int kvt = blk & 15;
  const int h   = (blk >> 4) & 7;
  const int b   = blk >> 7;
  const int t  = threadIdx.x;
  const int r  = t >> 4;
  const int c4 = (t & 15) << 2;

#pragma unroll
  for (int i = 0; i < 4; ++i) {
    const int kvl = r + 16 * i;
    float4 v = *(const float4*)(k + (size_t)(b * SKV_ + kvt * 64 + kvl) * DE + h * DH + c4);
    tile[kvl][c4 + 0] = v.x; tile[kvl][c4 + 1] = v.y;
    tile[kvl][c4 + 2] = v.z; tile[kvl][c4 + 3] = v.w;
  }
  __syncthreads();
#pragma unroll
  for (int i = 0; i < 4; ++i) {
    const int d = r + 16 * i;
    float4 o;
    o.x = tile[c4 + 0][d]; o.y = tile[c4 + 1][d];
    o.z = tile[c4 + 2][d]; o.w = tile[c4 + 3][d];
    *(float4*)(kt + (size_t)((b * 8 + h) * 64 + d) * SKV_ + kvt * 64 + c4) = o;
  }
}

// ---------------------------------------------------------------------------
// Fused sparse attention v3: wave owns 4 FULL rows (1024 kv in 64 regs).
// No barriers after Q-stage; all reductions are in-wave shuffles.
// kv mapping: kv = c*256 + 4*l + j  (c=0..3 float4 slot, j component).
// XCD swizzle: batch b pinned to one XCD -> K/V tile L2-resident.
// ---------------------------------------------------------------------------
__global__ __launch_bounds__(256, 4)
void attn_sparse_v3(const float* __restrict__ qb, const float* __restrict__ kt,
                    const float* __restrict__ vb, float* __restrict__ ob) {
  __shared__ float Qs[TQ][64];

  const int phys = blockIdx.x;
  const int bid = (phys & 7) * 1024 + (phys >> 3);   // 8192 blocks, bijective
  const int qt = bid & 127;
  const int h  = (bid >> 7) & 7;
  const int b  = bid >> 10;
  const int t  = threadIdx.x;
  const int w  = t >> 6;
  const int l  = t & 63;

  // stage Q tile, pre-scaled by 1/8 (exact: power of two)
  {
    const int r = t >> 4, d4 = (t & 15) << 2;
    float4 qv = *(const float4*)(qb + (size_t)(b * SQ_ + qt * TQ + r) * DE + h * DH + d4);
    qv.x *= 0.125f; qv.y *= 0.125f; qv.z *= 0.125f; qv.w *= 0.125f;
    *(float4*)&Qs[r][d4] = qv;
  }
  __syncthreads();

  const int r0 = w * 4;

  // ---- QK^T into registers
  float4 s4[4][4];
#pragma unroll
  for (int q = 0; q < 4; ++q)
#pragma unroll
    for (int c = 0; c < 4; ++c) s4[q][c] = make_float4(0.f, 0.f, 0.f, 0.f);

  const char* kp = (const char*)(kt + (size_t)((b * 8 + h) * 64) * SKV_ + 4 * l);
#pragma unroll 2
  for (int d = 0; d < 64; d += 2) {
    float4 k00 = *(const float4*)(kp);
    float4 k01 = *(const float4*)(kp + 1024);
    float4 k02 = *(const float4*)(kp + 2048);
    float4 k03 = *(const float4*)(kp + 3072);
    float4 k10 = *(const float4*)(kp + 4096);
    float4 k11 = *(const float4*)(kp + 5120);
    float4 k12 = *(const float4*)(kp + 6144);
    float4 k13 = *(const float4*)(kp + 7168);
    kp += 8192;
#pragma unroll
    for (int q = 0; q < 4; ++q) {
      float2 qv = *(const float2*)&Qs[r0 + q][d];
      FMA4(s4[q][0], qv.x, k00);
      FMA4(s4[q][1], qv.x, k01);
      FMA4(s4[q][2], qv.x, k02);
      FMA4(s4[q][3], qv.x, k03);
      FMA4(s4[q][0], qv.y, k10);
      FMA4(s4[q][1], qv.y, k11);
      FMA4(s4[q][2], qv.y, k12);
      FMA4(s4[q][3], qv.y, k13);
    }
  }

  const float* vB = vb + (size_t)(b * SKV_) * DE + h * DH + l;

  // ---- per-row softmax -> entropy -> top_k -> threshold -> sparse PV
#pragma unroll
  for (int q = 0; q < 4; ++q) {
    float* sr = (float*)&s4[q][0];   // 16 contiguous reg-resident floats

    float lm = -INFINITY;
#pragma unroll
    for (int i = 0; i < 16; ++i) lm = fmaxf(lm, sr[i]);
    const float m = wredmax(lm);

    float zl = 0.f, hl = 0.f;
#pragma unroll
    for (int i = 0; i < 16; ++i) {
      const float sv = sr[i] - m;
      const float p = expf(sv);
      sr[i] = p;
      zl += p;
      hl = fmaf(p, sv, hl);
    }
    const float Z = wredsum(zl);
    const float H = wredsum(hl);

    const float E = logf(Z) - H / Z;    // == -sum w log w (margin ~190 on tk)
    int tk = (int)(32.0f * (1.0f - E));
    tk = tk < 1 ? 1 : (tk > 32 ? 32 : tk);

    const float rZ = 1.0f / Z;
#pragma unroll
    for (int i = 0; i < 16; ++i) sr[i] *= rZ;   // w values

    // exact duplicate-aware tk-th-largest threshold (all in-wave)
    float cur = INFINITY, thr = 0.f, rem = (float)tk;
    while (true) {
      float lmx = -INFINITY;
#pragma unroll
      for (int i = 0; i < 16; ++i) {
        const float wv = sr[i];
        if (wv < cur) lmx = fmaxf(lmx, wv);
      }
      const float m2 = wredmax(lmx);
      float lc = 0.f;
#pragma unroll
      for (int i = 0; i < 16; ++i) lc += (sr[i] == m2) ? 1.f : 0.f;
      const float c = wredsum(lc);
      if (c >= rem) { thr = m2; break; }
      rem -= c; cur = m2;
    }

    // sparse PV: lane <-> head dim; psel via broadcast accumulation
    float acc = 0.f, psel = 0.f;
#pragma unroll
    for (int c = 0; c < 4; ++c) {
#pragma unroll
      for (int j = 0; j < 4; ++j) {
        const float wv0 = sr[c * 4 + j];
        unsigned long long msk = __ballot(wv0 >= thr);
        while (msk) {
          const int bit = __builtin_ctzll(msk);
          msk &= msk - 1;
          const float wv = __shfl(wv0, bit);
          psel += wv;
          const int kv = c * 256 + 4 * bit + j;
          acc = fmaf(wv, vB[(size_t)kv * DE], acc);
        }
      }
    }
    ob[(size_t)(b * SQ_ + qt * TQ + r0 + q) * DE + h * DH + l] = acc / (psel + 1e-8f);
  }
}

// ---------------------------------------------------------------------------
extern "C" void kernel_launch(void* const* d_in, const int* in_sizes, int n_in,
                              void* d_out, int out_size, void* d_ws, size_t ws_size,
                              hipStream_t stream) {
  const float* x  = (const float*)d_in[0];
  const float* y  = (const float*)d_in[1];
  const float* wq = (const float*)d_in[2];
  const float* bq = (const float*)d_in[3];
  const float* wk = (const float*)d_in[4];
  const float* bk = (const float*)d_in[5];
  const float* wv = (const float*)d_in[6];
  const float* bv = (const float*)d_in[7];
  const float* wo = (const float*)d_in[8];
  const float* bo = (const float*)d_in[9];
  float* out = (float*)d_out;

  char* ws = (char*)d_ws;
  float* q  = (float*)(ws);                         // 32MB
  float* k  = (float*)(ws + (size_t)32 * 1048576);  // 16MB
  float* v  = (float*)(ws + (size_t)48 * 1048576);  // 16MB
  float* ao = (float*)(ws + (size_t)64 * 1048576);  // 32MB
  float* kt = (float*)(ws + (size_t)96 * 1048576);  // 16MB

  dim3 blk(256);
  gemm_bias_f32<<<dim3(4, 128), blk, 0, stream>>>(x, wq, bq, q, 16384, 512, 512);
  gemm_bias_f32<<<dim3(4, 64), blk, 0, stream>>>(y, wk, bk, k, 8192, 512, 768);
  gemm_bias_f32<<<dim3(4, 64), blk, 0, stream>>>(y, wv, bv, v, 8192, 512, 768);
  transpose_k<<<dim3(1024), blk, 0, stream>>>(k, kt);
  attn_sparse_v3<<<dim3(8 * N_HEADS * (SQ_ / TQ)), blk, 0, stream>>>(q, kt, v, ao);
  gemm_bias_f32<<<dim3(4, 128), blk, 0, stream>>>(ao, wo, bo, out, 16384, 512, 512);
}

// Round 4
// 536.121 us; speedup vs baseline: 4.0262x; 1.5095x over previous
//
#include <hip/hip_runtime.h>
#include <cstdint>
#include <cmath>

#define N_HEADS 8
#define DH      64
#define SQ_     2048
#define SKV_    1024
#define DE      512
#define TQ      16

typedef _Float16 f16;
typedef _Float16 f16x8 __attribute__((ext_vector_type(8)));
typedef float f32x4 __attribute__((ext_vector_type(4)));

__device__ __forceinline__ float wredmax(float v) {
#pragma unroll
  for (int o = 32; o > 0; o >>= 1) v = fmaxf(v, __shfl_xor(v, o));
  return v;
}
__device__ __forceinline__ float wredsum(float v) {
#pragma unroll
  for (int o = 32; o > 0; o >>= 1) v += __shfl_xor(v, o);
  return v;
}

#define FMA4(d, a, b) \
  d.x = fmaf(a, b.x, d.x); d.y = fmaf(a, b.y, d.y); \
  d.z = fmaf(a, b.z, d.z); d.w = fmaf(a, b.w, d.w)

// ---------------------------------------------------------------------------
// Split fp32 -> (hi, lo) fp16 pair, optional pre-scale.
// ---------------------------------------------------------------------------
__global__ __launch_bounds__(256)
void split_f16(const float* __restrict__ in, f16* __restrict__ hi,
               f16* __restrict__ lo, int n4, float scale) {
  const int i = blockIdx.x * 256 + threadIdx.x;
  if (i >= n4) return;
  float4 v = ((const float4*)in)[i];
  v.x *= scale; v.y *= scale; v.z *= scale; v.w *= scale;
  f16 h0 = (f16)v.x, h1 = (f16)v.y, h2 = (f16)v.z, h3 = (f16)v.w;
  f16 l0 = (f16)(v.x - (float)h0), l1 = (f16)(v.y - (float)h1);
  f16 l2 = (f16)(v.z - (float)h2), l3 = (f16)(v.w - (float)h3);
  f16 hb[4] = {h0, h1, h2, h3};
  f16 lb[4] = {l0, l1, l2, l3};
  ((uint2*)hi)[i] = *(const uint2*)hb;
  ((uint2*)lo)[i] = *(const uint2*)lb;
}

// ---------------------------------------------------------------------------
// MFMA f16 GEMM: C[M,N] = (Ah+Al)[M,K] @ ((Wh+Wl)[N,K])^T * inv + bias[N]
// NSPLIT=1: C = Ah @ Wh^T + bias.  NSPLIT=3: hh + h*l + l*h products.
// 128x128 tile, BK=32, 4 waves (2x2), 64x64 per wave, 16x16x32 MFMA.
// Reg-staged LDS with XOR chunk swizzle; loads for next step issued
// before compute (T14 split).
// ---------------------------------------------------------------------------
template <int NSPLIT>
__global__ __launch_bounds__(256, 2)
void gemm_f16(const f16* __restrict__ Ah, const f16* __restrict__ Al,
              const f16* __restrict__ Wh, const f16* __restrict__ Wl,
              const float* __restrict__ bias, float* __restrict__ C,
              int M, int N, int K, float inv) {
  __shared__ f16 smem[(NSPLIT == 3 ? 4 : 2) * 4096];
  f16* As  = smem;
  f16* Als = (NSPLIT == 3) ? smem + 4096 : nullptr;
  f16* Ws  = smem + (NSPLIT == 3 ? 8192 : 4096);
  f16* Wls = (NSPLIT == 3) ? smem + 12288 : nullptr;

  const int tid = threadIdx.x;
  const int w = tid >> 6;
  const int l = tid & 63;
  const int wm = w >> 1, wn = w & 1;
  const int m0 = blockIdx.y * 128;
  const int n0 = blockIdx.x * 128;

  // staging thread mapping: row = tid>>2 (+64), global chunk = tid&3
  const int srow = tid >> 2;
  const int schk = tid & 3;
  const f16* pA  = Ah + (size_t)(m0 + srow) * K + schk * 8;
  const f16* pW  = Wh + (size_t)(n0 + srow) * K + schk * 8;
  const f16* pAl = (NSPLIT == 3) ? Al + (size_t)(m0 + srow) * K + schk * 8 : nullptr;
  const f16* pWl = (NSPLIT == 3) ? Wl + (size_t)(n0 + srow) * K + schk * 8 : nullptr;
  const size_t rowskip = (size_t)64 * K;

  // LDS write offsets (XOR chunk swizzle within 64B rows)
  const int d0 = srow * 32 + ((schk ^ (srow & 3)) * 8);

  // fragment read offsets
  const int fbase = (l & 15) * 32 + (((l >> 4) ^ (l & 3)) * 8);
  const int fA = wm * 2048 + fbase;
  const int fW = wn * 2048 + fbase;

  f32x4 acc[4][4] = {};
  uint4 rA0, rA1, rW0, rW1, rAl0, rAl1, rWl0, rWl1;

  // prologue: load step 0
  rA0 = *(const uint4*)(pA);            rA1 = *(const uint4*)(pA + rowskip);
  rW0 = *(const uint4*)(pW);            rW1 = *(const uint4*)(pW + rowskip);
  if constexpr (NSPLIT == 3) {
    rAl0 = *(const uint4*)(pAl);        rAl1 = *(const uint4*)(pAl + rowskip);
    rWl0 = *(const uint4*)(pWl);        rWl1 = *(const uint4*)(pWl + rowskip);
  }

  for (int k0 = 0; k0 < K; k0 += 32) {
    __syncthreads();   // previous step's LDS fully consumed
    *(uint4*)&As[d0] = rA0;  *(uint4*)&As[d0 + 2048] = rA1;
    *(uint4*)&Ws[d0] = rW0;  *(uint4*)&Ws[d0 + 2048] = rW1;
    if constexpr (NSPLIT == 3) {
      *(uint4*)&Als[d0] = rAl0;  *(uint4*)&Als[d0 + 2048] = rAl1;
      *(uint4*)&Wls[d0] = rWl0;  *(uint4*)&Wls[d0 + 2048] = rWl1;
    }
    __syncthreads();   // tile visible

    if (k0 + 32 < K) {   // issue next-step loads; latency hides under MFMAs
      rA0 = *(const uint4*)(pA + k0 + 32);  rA1 = *(const uint4*)(pA + rowskip + k0 + 32);
      rW0 = *(const uint4*)(pW + k0 + 32);  rW1 = *(const uint4*)(pW + rowskip + k0 + 32);
      if constexpr (NSPLIT == 3) {
        rAl0 = *(const uint4*)(pAl + k0 + 32); rAl1 = *(const uint4*)(pAl + rowskip + k0 + 32);
        rWl0 = *(const uint4*)(pWl + k0 + 32); rWl1 = *(const uint4*)(pWl + rowskip + k0 + 32);
      }
    }

    f16x8 ah[4], wh[4], al[4], wl[4];
#pragma unroll
    for (int i = 0; i < 4; ++i) ah[i] = *(const f16x8*)&As[fA + i * 512];
#pragma unroll
    for (int j = 0; j < 4; ++j) wh[j] = *(const f16x8*)&Ws[fW + j * 512];
    if constexpr (NSPLIT == 3) {
#pragma unroll
      for (int i = 0; i < 4; ++i) al[i] = *(const f16x8*)&Als[fA + i * 512];
#pragma unroll
      for (int j = 0; j < 4; ++j) wl[j] = *(const f16x8*)&Wls[fW + j * 512];
    }

#pragma unroll
    for (int i = 0; i < 4; ++i)
#pragma unroll
      for (int j = 0; j < 4; ++j)
        acc[i][j] = __builtin_amdgcn_mfma_f32_16x16x32_f16(ah[i], wh[j], acc[i][j], 0, 0, 0);
    if constexpr (NSPLIT == 3) {
#pragma unroll
      for (int i = 0; i < 4; ++i)
#pragma unroll
        for (int j = 0; j < 4; ++j)
          acc[i][j] = __builtin_amdgcn_mfma_f32_16x16x32_f16(ah[i], wl[j], acc[i][j], 0, 0, 0);
#pragma unroll
      for (int i = 0; i < 4; ++i)
#pragma unroll
        for (int j = 0; j < 4; ++j)
          acc[i][j] = __builtin_amdgcn_mfma_f32_16x16x32_f16(al[i], wh[j], acc[i][j], 0, 0, 0);
    }
  }

  // epilogue: D row = (l>>4)*4 + r, col = l&15
  const int rr = (l >> 4) * 4;
  const int cc = l & 15;
#pragma unroll
  for (int j = 0; j < 4; ++j) {
    const int n = n0 + wn * 64 + j * 16 + cc;
    const float bv = bias[n];
#pragma unroll
    for (int i = 0; i < 4; ++i) {
      const int m = m0 + wm * 64 + i * 16 + rr;
#pragma unroll
      for (int r = 0; r < 4; ++r)
        C[(size_t)(m + r) * N + n] = acc[i][j][r] * inv + bv;
    }
  }
}

// ---------------------------------------------------------------------------
// fp32 GEMM (R3) — fallback path only.
// ---------------------------------------------------------------------------
__global__ __launch_bounds__(256)
void gemm_bias_f32(const float* __restrict__ A, const float* __restrict__ W,
                   const float* __restrict__ bias, float* __restrict__ C,
                   int M, int N, int K) {
  __shared__ float As[2][8][132];
  __shared__ float Ws[2][8][132];
  const int t  = threadIdx.x;
  const int tx = t & 15;
  const int ty = t >> 4;
  const int m0 = blockIdx.y * 128;
  const int n0 = blockIdx.x * 128;
  const int lr = t >> 1;
  const int lc = (t & 1) * 4;

  const float* Ap = A + (size_t)(m0 + lr) * K + lc;
  const float* Wp = W + (size_t)(n0 + lr) * K + lc;

  float acc[8][8] = {};
  {
    float4 av = *(const float4*)(Ap);
    float4 wv = *(const float4*)(Wp);
    As[0][lc + 0][lr] = av.x; As[0][lc + 1][lr] = av.y;
    As[0][lc + 2][lr] = av.z; As[0][lc + 3][lr] = av.w;
    Ws[0][lc + 0][lr] = wv.x; Ws[0][lc + 1][lr] = wv.y;
    Ws[0][lc + 2][lr] = wv.z; Ws[0][lc + 3][lr] = wv.w;
  }
  __syncthreads();

  int buf = 0;
  for (int k0 = 8; k0 < K; k0 += 8) {
    float4 av = *(const float4*)(Ap + k0);
    float4 wv = *(const float4*)(Wp + k0);
#pragma unroll
    for (int kk = 0; kk < 8; ++kk) {
      float a[8], b[8];
      *(float4*)&a[0] = *(const float4*)&As[buf][kk][ty * 8];
      *(float4*)&a[4] = *(const float4*)&As[buf][kk][ty * 8 + 4];
      *(float4*)&b[0] = *(const float4*)&Ws[buf][kk][tx * 8];
      *(float4*)&b[4] = *(const float4*)&Ws[buf][kk][tx * 8 + 4];
#pragma unroll
      for (int i = 0; i < 8; ++i)
#pragma unroll
        for (int j = 0; j < 8; ++j) acc[i][j] = fmaf(a[i], b[j], acc[i][j]);
    }
    const int nb = buf ^ 1;
    As[nb][lc + 0][lr] = av.x; As[nb][lc + 1][lr] = av.y;
    As[nb][lc + 2][lr] = av.z; As[nb][lc + 3][lr] = av.w;
    Ws[nb][lc + 0][lr] = wv.x; Ws[nb][lc + 1][lr] = wv.y;
    Ws[nb][lc + 2][lr] = wv.z; Ws[nb][lc + 3][lr] = wv.w;
    __syncthreads();
    buf = nb;
  }
#pragma unroll
  for (int kk = 0; kk < 8; ++kk) {
    float a[8], b[8];
    *(float4*)&a[0] = *(const float4*)&As[buf][kk][ty * 8];
    *(float4*)&a[4] = *(const float4*)&As[buf][kk][ty * 8 + 4];
    *(float4*)&b[0] = *(const float4*)&Ws[buf][kk][tx * 8];
    *(float4*)&b[4] = *(const float4*)&Ws[buf][kk][tx * 8 + 4];
#pragma unroll
    for (int i = 0; i < 8; ++i)
#pragma unroll
      for (int j = 0; j < 8; ++j) acc[i][j] = fmaf(a[i], b[j], acc[i][j]);
  }

  float4 b0 = *(const float4*)(bias + n0 + tx * 8);
  float4 b1 = *(const float4*)(bias + n0 + tx * 8 + 4);
#pragma unroll
  for (int i = 0; i < 8; ++i) {
    const int m = m0 + ty * 8 + i;
    float* Crow = C + (size_t)m * N + n0 + tx * 8;
    float4 o0, o1;
    o0.x = acc[i][0] + b0.x; o0.y = acc[i][1] + b0.y;
    o0.z = acc[i][2] + b0.z; o0.w = acc[i][3] + b0.w;
    o1.x = acc[i][4] + b1.x; o1.y = acc[i][5] + b1.y;
    o1.z = acc[i][6] + b1.z; o1.w = acc[i][7] + b1.w;
    *(float4*)Crow = o0;
    *(float4*)(Crow + 4) = o1;
  }
}

// ---------------------------------------------------------------------------
// K transpose: k[b, kv, h*64+d] -> kt[(b*8+h)*64 + d][kv]
// ---------------------------------------------------------------------------
__global__ __launch_bounds__(256)
void transpose_k(const float* __restrict__ k, float* __restrict__ kt) {
  __shared__ float tile[64][65];
  const int blk = blockIdx.x;
  const int kvt = blk & 15;
  const int h   = (blk >> 4) & 7;
  const int b   = blk >> 7;
  const int t  = threadIdx.x;
  const int r  = t >> 4;
  const int c4 = (t & 15) << 2;

#pragma unroll
  for (int i = 0; i < 4; ++i) {
    const int kvl = r + 16 * i;
    float4 v = *(const float4*)(k + (size_t)(b * SKV_ + kvt * 64 + kvl) * DE + h * DH + c4);
    tile[kvl][c4 + 0] = v.x; tile[kvl][c4 + 1] = v.y;
    tile[kvl][c4 + 2] = v.z; tile[kvl][c4 + 3] = v.w;
  }
  __syncthreads();
#pragma unroll
  for (int i = 0; i < 4; ++i) {
    const int d = r + 16 * i;
    float4 o;
    o.x = tile[c4 + 0][d]; o.y = tile[c4 + 1][d];
    o.z = tile[c4 + 2][d]; o.w = tile[c4 + 3][d];
    *(float4*)(kt + (size_t)((b * 8 + h) * 64 + d) * SKV_ + kvt * 64 + c4) = o;
  }
}

// ---------------------------------------------------------------------------
// Fused sparse attention v3 (R3), output type templated (f16 for MFMA O-proj).
// ---------------------------------------------------------------------------
template <typename OT>
__global__ __launch_bounds__(256, 4)
void attn_sparse_v3(const float* __restrict__ qb, const float* __restrict__ kt,
                    const float* __restrict__ vb, OT* __restrict__ ob) {
  __shared__ float Qs[TQ][64];

  const int phys = blockIdx.x;
  const int bid = (phys & 7) * 1024 + (phys >> 3);
  const int qt = bid & 127;
  const int h  = (bid >> 7) & 7;
  const int b  = bid >> 10;
  const int t  = threadIdx.x;
  const int w  = t >> 6;
  const int l  = t & 63;

  {
    const int r = t >> 4, d4 = (t & 15) << 2;
    float4 qv = *(const float4*)(qb + (size_t)(b * SQ_ + qt * TQ + r) * DE + h * DH + d4);
    qv.x *= 0.125f; qv.y *= 0.125f; qv.z *= 0.125f; qv.w *= 0.125f;
    *(float4*)&Qs[r][d4] = qv;
  }
  __syncthreads();

  const int r0 = w * 4;

  float4 s4[4][4];
#pragma unroll
  for (int q = 0; q < 4; ++q)
#pragma unroll
    for (int c = 0; c < 4; ++c) s4[q][c] = make_float4(0.f, 0.f, 0.f, 0.f);

  const char* kp = (const char*)(kt + (size_t)((b * 8 + h) * 64) * SKV_ + 4 * l);
#pragma unroll 2
  for (int d = 0; d < 64; d += 2) {
    float4 k00 = *(const float4*)(kp);
    float4 k01 = *(const float4*)(kp + 1024);
    float4 k02 = *(const float4*)(kp + 2048);
    float4 k03 = *(const float4*)(kp + 3072);
    float4 k10 = *(const float4*)(kp + 4096);
    float4 k11 = *(const float4*)(kp + 5120);
    float4 k12 = *(const float4*)(kp + 6144);
    float4 k13 = *(const float4*)(kp + 7168);
    kp += 8192;
#pragma unroll
    for (int q = 0; q < 4; ++q) {
      float2 qv = *(const float2*)&Qs[r0 + q][d];
      FMA4(s4[q][0], qv.x, k00);
      FMA4(s4[q][1], qv.x, k01);
      FMA4(s4[q][2], qv.x, k02);
      FMA4(s4[q][3], qv.x, k03);
      FMA4(s4[q][0], qv.y, k10);
      FMA4(s4[q][1], qv.y, k11);
      FMA4(s4[q][2], qv.y, k12);
      FMA4(s4[q][3], qv.y, k13);
    }
  }

  const float* vB = vb + (size_t)(b * SKV_) * DE + h * DH + l;

#pragma unroll
  for (int q = 0; q < 4; ++q) {
    float* sr = (float*)&s4[q][0];

    float lm = -INFINITY;
#pragma unroll
    for (int i = 0; i < 16; ++i) lm = fmaxf(lm, sr[i]);
    const float m = wredmax(lm);

    float zl = 0.f, hl = 0.f;
#pragma unroll
    for (int i = 0; i < 16; ++i) {
      const float sv = sr[i] - m;
      const float p = expf(sv);
      sr[i] = p;
      zl += p;
      hl = fmaf(p, sv, hl);
    }
    const float Z = wredsum(zl);
    const float H = wredsum(hl);

    const float E = logf(Z) - H / Z;
    int tk = (int)(32.0f * (1.0f - E));
    tk = tk < 1 ? 1 : (tk > 32 ? 32 : tk);

    const float rZ = 1.0f / Z;
#pragma unroll
    for (int i = 0; i < 16; ++i) sr[i] *= rZ;

    float cur = INFINITY, thr = 0.f, rem = (float)tk;
    while (true) {
      float lmx = -INFINITY;
#pragma unroll
      for (int i = 0; i < 16; ++i) {
        const float wv = sr[i];
        if (wv < cur) lmx = fmaxf(lmx, wv);
      }
      const float m2 = wredmax(lmx);
      float lc = 0.f;
#pragma unroll
      for (int i = 0; i < 16; ++i) lc += (sr[i] == m2) ? 1.f : 0.f;
      const float c = wredsum(lc);
      if (c >= rem) { thr = m2; break; }
      rem -= c; cur = m2;
    }

    float acc = 0.f, psel = 0.f;
#pragma unroll
    for (int c = 0; c < 4; ++c) {
#pragma unroll
      for (int j = 0; j < 4; ++j) {
        const float wv0 = sr[c * 4 + j];
        unsigned long long msk = __ballot(wv0 >= thr);
        while (msk) {
          const int bit = __builtin_ctzll(msk);
          msk &= msk - 1;
          const float wv = __shfl(wv0, bit);
          psel += wv;
          const int kv = c * 256 + 4 * bit + j;
          acc = fmaf(wv, vB[(size_t)kv * DE], acc);
        }
      }
    }
    ob[(size_t)(b * SQ_ + qt * TQ + r0 + q) * DE + h * DH + l] = (OT)(acc / (psel + 1e-8f));
  }
}

// ---------------------------------------------------------------------------
extern "C" void kernel_launch(void* const* d_in, const int* in_sizes, int n_in,
                              void* d_out, int out_size, void* d_ws, size_t ws_size,
                              hipStream_t stream) {
  const float* x  = (const float*)d_in[0];
  const float* y  = (const float*)d_in[1];
  const float* wq = (const float*)d_in[2];
  const float* bq = (const float*)d_in[3];
  const float* wk = (const float*)d_in[4];
  const float* bk = (const float*)d_in[5];
  const float* wv = (const float*)d_in[6];
  const float* bv = (const float*)d_in[7];
  const float* wo = (const float*)d_in[8];
  const float* bo = (const float*)d_in[9];
  float* out = (float*)d_out;

  char* ws = (char*)d_ws;
  const size_t MiB = 1048576;
  dim3 blk(256);

  if (ws_size >= 141 * MiB) {
    // ---- MFMA path ----
    float* q   = (float*)(ws);                  // 32 MiB
    float* kt  = (float*)(ws + 32 * MiB);       // 16
    float* v   = (float*)(ws + 48 * MiB);       // 16
    f16* xh    = (f16*)(ws + 64 * MiB);         // 16
    f16* xl    = (f16*)(ws + 80 * MiB);         // 16
    f16* yh    = (f16*)(ws + 96 * MiB);         // 12
    f16* yl    = (f16*)(ws + 108 * MiB);        // 12
    float* k   = (float*)(ws + 120 * MiB);      // 16 (aliased with ao)
    f16* ao    = (f16*)(ws + 120 * MiB);
    f16* wqh   = (f16*)(ws + 136 * MiB);
    f16* wql   = (f16*)(ws + 136 * MiB + 524288);
    f16* wkh   = (f16*)(ws + 137 * MiB);
    f16* wkl   = (f16*)(ws + 137 * MiB + 786432);
    f16* wvh   = (f16*)(ws + 137 * MiB + 2 * 786432);
    f16* wvl   = (f16*)(ws + 137 * MiB + 3 * 786432);
    f16* woh   = (f16*)(ws + 140 * MiB);
    f16* wol   = (f16*)(ws + 140 * MiB + 524288);

    const float WS = 2048.0f, IWS = 1.0f / 2048.0f;
    split_f16<<<dim3(8192), blk, 0, stream>>>(x, xh, xl, 2097152, 1.0f);
    split_f16<<<dim3(6144), blk, 0, stream>>>(y, yh, yl, 1572864, 1.0f);
    split_f16<<<dim3(256),  blk, 0, stream>>>(wq, wqh, wql, 65536, WS);
    split_f16<<<dim3(384),  blk, 0, stream>>>(wk, wkh, wkl, 98304, WS);
    split_f16<<<dim3(384),  blk, 0, stream>>>(wv, wvh, wvl, 98304, 1.0f);
    split_f16<<<dim3(256),  blk, 0, stream>>>(wo, woh, wol, 65536, 1.0f);

    gemm_f16<3><<<dim3(4, 128), blk, 0, stream>>>(xh, xl, wqh, wql, bq, q, 16384, 512, 512, IWS);
    gemm_f16<3><<<dim3(4, 64),  blk, 0, stream>>>(yh, yl, wkh, wkl, bk, k, 8192, 512, 768, IWS);
    gemm_f16<1><<<dim3(4, 64),  blk, 0, stream>>>(yh, nullptr, wvh, nullptr, bv, v, 8192, 512, 768, 1.0f);
    transpose_k<<<dim3(1024), blk, 0, stream>>>(k, kt);
    attn_sparse_v3<f16><<<dim3(8192), blk, 0, stream>>>(q, kt, v, ao);
    gemm_f16<1><<<dim3(4, 128), blk, 0, stream>>>(ao, nullptr, woh, nullptr, bo, out, 16384, 512, 512, 1.0f);
  } else {
    // ---- fallback: R3 fp32 path (needs 112 MiB) ----
    float* q  = (float*)(ws);
    float* k  = (float*)(ws + 32 * MiB);
    float* v  = (float*)(ws + 48 * MiB);
    float* ao = (float*)(ws + 64 * MiB);
    float* kt = (float*)(ws + 96 * MiB);

    gemm_bias_f32<<<dim3(4, 128), blk, 0, stream>>>(x, wq, bq, q, 16384, 512, 512);
    gemm_bias_f32<<<dim3(4, 64), blk, 0, stream>>>(y, wk, bk, k, 8192, 512, 768);
    gemm_bias_f32<<<dim3(4, 64), blk, 0, stream>>>(y, wv, bv, v, 8192, 512, 768);
    transpose_k<<<dim3(1024), blk, 0, stream>>>(k, kt);
    attn_sparse_v3<float><<<dim3(8192), blk, 0, stream>>>(q, kt, v, ao);
    gemm_bias_f32<<<dim3(4, 128), blk, 0, stream>>>(ao, wo, bo, out, 16384, 512, 512);
  }
}

// Round 5
// 389.459 us; speedup vs baseline: 5.5424x; 1.3766x over previous
//
#include <hip/hip_runtime.h>
#include <cstdint>
#include <cmath>

#define DH 64
#define SQB 2048
#define SKVB 1024
#define DE 512

typedef _Float16 f16;
typedef _Float16 f16x8 __attribute__((ext_vector_type(8)));
typedef float f32x4 __attribute__((ext_vector_type(4)));

// ---------------------------------------------------------------------------
// Split fp32 -> (hi, lo) fp16 pair, optional pre-scale.
// ---------------------------------------------------------------------------
__global__ __launch_bounds__(256)
void split_f16(const float* __restrict__ in, f16* __restrict__ hi,
               f16* __restrict__ lo, int n4, float scale) {
  const int i = blockIdx.x * 256 + threadIdx.x;
  if (i >= n4) return;
  float4 v = ((const float4*)in)[i];
  v.x *= scale; v.y *= scale; v.z *= scale; v.w *= scale;
  f16 h0 = (f16)v.x, h1 = (f16)v.y, h2 = (f16)v.z, h3 = (f16)v.w;
  f16 l0 = (f16)(v.x - (float)h0), l1 = (f16)(v.y - (float)h1);
  f16 l2 = (f16)(v.z - (float)h2), l3 = (f16)(v.w - (float)h3);
  f16 hb[4] = {h0, h1, h2, h3};
  f16 lb[4] = {l0, l1, l2, l3};
  ((uint2*)hi)[i] = *(const uint2*)hb;
  ((uint2*)lo)[i] = *(const uint2*)lb;
}

// ---------------------------------------------------------------------------
// MFMA f16 GEMM (R4-validated core). OUT=0: C fp32. OUT=1: split-f16 pair
// (hi/lo) of (C * oscale) — fuses the downstream split kernel.
// ---------------------------------------------------------------------------
template <int NSPLIT, int OUT>
__global__ __launch_bounds__(256, 2)
void gemm_f16(const f16* __restrict__ Ah, const f16* __restrict__ Al,
              const f16* __restrict__ Wh, const f16* __restrict__ Wl,
              const float* __restrict__ bias, float* __restrict__ C,
              f16* __restrict__ Ch, f16* __restrict__ Cl,
              int M, int N, int K, float inv, float oscale) {
  __shared__ f16 smem[(NSPLIT == 3 ? 4 : 2) * 4096];
  f16* As  = smem;
  f16* Als = (NSPLIT == 3) ? smem + 4096 : nullptr;
  f16* Ws  = smem + (NSPLIT == 3 ? 8192 : 4096);
  f16* Wls = (NSPLIT == 3) ? smem + 12288 : nullptr;

  const int tid = threadIdx.x;
  const int w = tid >> 6;
  const int l = tid & 63;
  const int wm = w >> 1, wn = w & 1;
  const int m0 = blockIdx.y * 128;
  const int n0 = blockIdx.x * 128;

  const int srow = tid >> 2;
  const int schk = tid & 3;
  const f16* pA  = Ah + (size_t)(m0 + srow) * K + schk * 8;
  const f16* pW  = Wh + (size_t)(n0 + srow) * K + schk * 8;
  const f16* pAl = (NSPLIT == 3) ? Al + (size_t)(m0 + srow) * K + schk * 8 : nullptr;
  const f16* pWl = (NSPLIT == 3) ? Wl + (size_t)(n0 + srow) * K + schk * 8 : nullptr;
  const size_t rowskip = (size_t)64 * K;

  const int d0 = srow * 32 + ((schk ^ (srow & 3)) * 8);
  const int fbase = (l & 15) * 32 + (((l >> 4) ^ (l & 3)) * 8);
  const int fA = wm * 2048 + fbase;
  const int fW = wn * 2048 + fbase;

  f32x4 acc[4][4] = {};
  uint4 rA0, rA1, rW0, rW1, rAl0, rAl1, rWl0, rWl1;

  rA0 = *(const uint4*)(pA);            rA1 = *(const uint4*)(pA + rowskip);
  rW0 = *(const uint4*)(pW);            rW1 = *(const uint4*)(pW + rowskip);
  if constexpr (NSPLIT == 3) {
    rAl0 = *(const uint4*)(pAl);        rAl1 = *(const uint4*)(pAl + rowskip);
    rWl0 = *(const uint4*)(pWl);        rWl1 = *(const uint4*)(pWl + rowskip);
  }

  for (int k0 = 0; k0 < K; k0 += 32) {
    __syncthreads();
    *(uint4*)&As[d0] = rA0;  *(uint4*)&As[d0 + 2048] = rA1;
    *(uint4*)&Ws[d0] = rW0;  *(uint4*)&Ws[d0 + 2048] = rW1;
    if constexpr (NSPLIT == 3) {
      *(uint4*)&Als[d0] = rAl0;  *(uint4*)&Als[d0 + 2048] = rAl1;
      *(uint4*)&Wls[d0] = rWl0;  *(uint4*)&Wls[d0 + 2048] = rWl1;
    }
    __syncthreads();

    if (k0 + 32 < K) {
      rA0 = *(const uint4*)(pA + k0 + 32);  rA1 = *(const uint4*)(pA + rowskip + k0 + 32);
      rW0 = *(const uint4*)(pW + k0 + 32);  rW1 = *(const uint4*)(pW + rowskip + k0 + 32);
      if constexpr (NSPLIT == 3) {
        rAl0 = *(const uint4*)(pAl + k0 + 32); rAl1 = *(const uint4*)(pAl + rowskip + k0 + 32);
        rWl0 = *(const uint4*)(pWl + k0 + 32); rWl1 = *(const uint4*)(pWl + rowskip + k0 + 32);
      }
    }

    f16x8 ah[4], wh[4], al[4], wl[4];
#pragma unroll
    for (int i = 0; i < 4; ++i) ah[i] = *(const f16x8*)&As[fA + i * 512];
#pragma unroll
    for (int j = 0; j < 4; ++j) wh[j] = *(const f16x8*)&Ws[fW + j * 512];
    if constexpr (NSPLIT == 3) {
#pragma unroll
      for (int i = 0; i < 4; ++i) al[i] = *(const f16x8*)&Als[fA + i * 512];
#pragma unroll
      for (int j = 0; j < 4; ++j) wl[j] = *(const f16x8*)&Wls[fW + j * 512];
    }

#pragma unroll
    for (int i = 0; i < 4; ++i)
#pragma unroll
      for (int j = 0; j < 4; ++j)
        acc[i][j] = __builtin_amdgcn_mfma_f32_16x16x32_f16(ah[i], wh[j], acc[i][j], 0, 0, 0);
    if constexpr (NSPLIT == 3) {
#pragma unroll
      for (int i = 0; i < 4; ++i)
#pragma unroll
        for (int j = 0; j < 4; ++j)
          acc[i][j] = __builtin_amdgcn_mfma_f32_16x16x32_f16(ah[i], wl[j], acc[i][j], 0, 0, 0);
#pragma unroll
      for (int i = 0; i < 4; ++i)
#pragma unroll
        for (int j = 0; j < 4; ++j)
          acc[i][j] = __builtin_amdgcn_mfma_f32_16x16x32_f16(al[i], wh[j], acc[i][j], 0, 0, 0);
    }
  }

  const int rr = (l >> 4) * 4;
  const int cc = l & 15;
#pragma unroll
  for (int j = 0; j < 4; ++j) {
    const int n = n0 + wn * 64 + j * 16 + cc;
    const float bv = bias[n];
#pragma unroll
    for (int i = 0; i < 4; ++i) {
      const int m = m0 + wm * 64 + i * 16 + rr;
#pragma unroll
      for (int r = 0; r < 4; ++r) {
        const float val = acc[i][j][r] * inv + bv;
        if constexpr (OUT == 0) {
          C[(size_t)(m + r) * N + n] = val;
        } else {
          const float sv = val * oscale;
          const f16 hh = (f16)sv;
          const f16 ll = (f16)(sv - (float)hh);
          Ch[(size_t)(m + r) * N + n] = hh;
          Cl[(size_t)(m + r) * N + n] = ll;
        }
      }
    }
  }
}

// ---------------------------------------------------------------------------
// Fused sparse attention v4: MFMA QK^T (split-3 f16), lane owns q-row l&15.
// Block = (b, h, 16 q-rows); wave w owns kv quarter [256w, 256w+256).
// S regs: S[t][r] = s_raw[q=l&15][kv = w*256 + t*16 + (l>>4)*4 + r],
// s_raw = 4096 * s_true (q pre-scaled x8, k x64).
// ---------------------------------------------------------------------------
__global__ __launch_bounds__(256, 3)
void attn_v4(const f16* __restrict__ qhb, const f16* __restrict__ qlb,
             const f16* __restrict__ khb, const f16* __restrict__ klb,
             const float* __restrict__ vb, f16* __restrict__ ob) {
  __shared__ float pM[4][16], pZ[4][16], pH[4][16], pC[4][16];
  __shared__ int cnt16[4][4][16];
  __shared__ int lkv[16][40];
  __shared__ float lpv[16][40];
  __shared__ int lcnt[16];

  const int phys = blockIdx.x;
  const int bid = (phys & 7) * 1024 + (phys >> 3);   // XCD swizzle, bijective
  const int qt = bid & 127;
  const int h  = (bid >> 7) & 7;
  const int b  = bid >> 10;
  const int tid = threadIdx.x;
  const int w = tid >> 6;
  const int l = tid & 63;
  const int q16 = l & 15;
  const int g = l >> 4;

  // ---- Q fragments (B operand): col=q16, k-chunk=g; two k-steps (d 0-31, 32-63)
  const size_t qoff = (size_t)(b * SQB + qt * 16 + q16) * DE + h * DH + g * 8;
  const f16x8 qf_h0 = *(const f16x8*)(qhb + qoff);
  const f16x8 qf_h1 = *(const f16x8*)(qhb + qoff + 32);
  const f16x8 qf_l0 = *(const f16x8*)(qlb + qoff);
  const f16x8 qf_l1 = *(const f16x8*)(qlb + qoff + 32);

  // ---- K pointers (A operand): row=q16 within tile, k-chunk=g
  const size_t koff = (size_t)(b * SKVB + w * 256 + q16) * DE + h * DH + g * 8;
  const f16* kp  = khb + koff;
  const f16* klp = klb + koff;

  f32x4 S[16];
#pragma unroll
  for (int i = 0; i < 16; ++i) S[i] = (f32x4){0.f, 0.f, 0.f, 0.f};

  f16x8 ka0 = *(const f16x8*)(kp);
  f16x8 ka1 = *(const f16x8*)(kp + 32);
  f16x8 kb0 = *(const f16x8*)(klp);
  f16x8 kb1 = *(const f16x8*)(klp + 32);
#pragma unroll
  for (int t = 0; t < 16; ++t) {
    f16x8 na0, na1, nb0, nb1;
    if (t < 15) {   // prefetch next 16-kv tile (tile stride = 16 rows * 512)
      na0 = *(const f16x8*)(kp + 8192);
      na1 = *(const f16x8*)(kp + 8192 + 32);
      nb0 = *(const f16x8*)(klp + 8192);
      nb1 = *(const f16x8*)(klp + 8192 + 32);
      kp += 8192; klp += 8192;
    }
    S[t] = __builtin_amdgcn_mfma_f32_16x16x32_f16(ka0, qf_h0, S[t], 0, 0, 0);
    S[t] = __builtin_amdgcn_mfma_f32_16x16x32_f16(ka0, qf_l0, S[t], 0, 0, 0);
    S[t] = __builtin_amdgcn_mfma_f32_16x16x32_f16(kb0, qf_h0, S[t], 0, 0, 0);
    S[t] = __builtin_amdgcn_mfma_f32_16x16x32_f16(ka1, qf_h1, S[t], 0, 0, 0);
    S[t] = __builtin_amdgcn_mfma_f32_16x16x32_f16(ka1, qf_l1, S[t], 0, 0, 0);
    S[t] = __builtin_amdgcn_mfma_f32_16x16x32_f16(kb1, qf_h1, S[t], 0, 0, 0);
    if (t < 15) { ka0 = na0; ka1 = na1; kb0 = nb0; kb1 = nb1; }
  }

  // ---- M1: row max (raw scale)
  float mx = -INFINITY;
#pragma unroll
  for (int t = 0; t < 16; ++t)
#pragma unroll
    for (int r = 0; r < 4; ++r) mx = fmaxf(mx, S[t][r]);
  mx = fmaxf(mx, __shfl_xor(mx, 16));
  mx = fmaxf(mx, __shfl_xor(mx, 32));
  if (g == 0) pM[w][q16] = mx;
  __syncthreads();
  const float m = fmaxf(fmaxf(pM[0][q16], pM[1][q16]), fmaxf(pM[2][q16], pM[3][q16]));

  // ---- M2: p = exp(sv/4096), Z, H (raw-units H, rescaled once)
  const float C2 = 1.44269504f / 4096.0f;   // log2(e)/4096
  float Zl = 0.f, Hl = 0.f;
#pragma unroll
  for (int t = 0; t < 16; ++t)
#pragma unroll
    for (int r = 0; r < 4; ++r) {
      const float sv = S[t][r] - m;          // <= 0; == 0 exactly at row max
      const float p = __builtin_amdgcn_exp2f(sv * C2);
      S[t][r] = p;
      Zl += p;
      Hl = fmaf(p, sv, Hl);
    }
  Zl += __shfl_xor(Zl, 16); Zl += __shfl_xor(Zl, 32);
  Hl += __shfl_xor(Hl, 16); Hl += __shfl_xor(Hl, 32);
  if (g == 0) { pZ[w][q16] = Zl; pH[w][q16] = Hl; }
  __syncthreads();
  const float Z = (pZ[0][q16] + pZ[1][q16]) + (pZ[2][q16] + pZ[3][q16]);
  const float Hraw = (pH[0][q16] + pH[1][q16]) + (pH[2][q16] + pH[3][q16]);
  const float E = __logf(Z) - (Hraw * (1.0f / 4096.0f)) / Z;
  int tk = (int)(32.0f * (1.0f - E));
  tk = tk < 1 ? 1 : (tk > 32 ? 32 : tk);

  // ---- M3: extraction (p-space). Pass 1: candidate is exactly 1.0 (row max).
  float thr = 0.f, cur = 1.0f, rem = (float)tk;
  bool pend;
  {
    float cl = 0.f;
#pragma unroll
    for (int t = 0; t < 16; ++t)
#pragma unroll
      for (int r = 0; r < 4; ++r) cl += (S[t][r] == 1.0f) ? 1.f : 0.f;
    cl += __shfl_xor(cl, 16); cl += __shfl_xor(cl, 32);
    if (g == 0) pC[w][q16] = cl;
    __syncthreads();
    const float c = (pC[0][q16] + pC[1][q16]) + (pC[2][q16] + pC[3][q16]);
    if (c >= rem) { thr = 1.0f; pend = false; }
    else { rem -= c; pend = true; }
  }
  int pass = 0;
  while (__ballot(pend) != 0ull && pass < 40) {
    ++pass;
    float lmx = -INFINITY;
#pragma unroll
    for (int t = 0; t < 16; ++t)
#pragma unroll
      for (int r = 0; r < 4; ++r) {
        const float p = S[t][r];
        lmx = (p < cur) ? fmaxf(lmx, p) : lmx;
      }
    lmx = fmaxf(lmx, __shfl_xor(lmx, 16));
    lmx = fmaxf(lmx, __shfl_xor(lmx, 32));
    if (g == 0) pM[w][q16] = lmx;
    __syncthreads();
    const float cand = fmaxf(fmaxf(pM[0][q16], pM[1][q16]), fmaxf(pM[2][q16], pM[3][q16]));
    float cl = 0.f;
#pragma unroll
    for (int t = 0; t < 16; ++t)
#pragma unroll
      for (int r = 0; r < 4; ++r) cl += (S[t][r] == cand) ? 1.f : 0.f;
    cl += __shfl_xor(cl, 16); cl += __shfl_xor(cl, 32);
    if (g == 0) pC[w][q16] = cl;
    __syncthreads();
    const float c = (pC[0][q16] + pC[1][q16]) + (pC[2][q16] + pC[3][q16]);
    if (pend) {
      if (c >= rem) { thr = cand; pend = false; }
      else { rem -= c; cur = cand; }
    }
  }

  // ---- M4: deterministic count-then-append of selected (kv, p)
  int nsel = 0;
#pragma unroll
  for (int t = 0; t < 16; ++t)
#pragma unroll
    for (int r = 0; r < 4; ++r) nsel += (S[t][r] >= thr) ? 1 : 0;
  cnt16[w][g][q16] = nsel;
  __syncthreads();
  int off = 0;
  {
    const int me = w * 4 + g;
#pragma unroll
    for (int ww = 0; ww < 4; ++ww)
#pragma unroll
      for (int gg = 0; gg < 4; ++gg)
        if (ww * 4 + gg < me) off += cnt16[ww][gg][q16];
  }
  if (w == 3 && g == 3) lcnt[q16] = off + nsel;
#pragma unroll
  for (int t = 0; t < 16; ++t)
#pragma unroll
    for (int r = 0; r < 4; ++r) {
      if (S[t][r] >= thr) {
        if (off < 40) {
          lkv[q16][off] = w * 256 + t * 16 + g * 4 + r;
          lpv[q16][off] = S[t][r];
        }
        ++off;
      }
    }
  __syncthreads();

  // ---- M5: PV. lane: row = tid>>4, d-chunk = (tid&15)*4.
  {
    const int row = tid >> 4;
    const int d4 = (tid & 15) * 4;
    int cnt = lcnt[row]; cnt = cnt > 40 ? 40 : cnt;
    const float Zr = (pZ[0][row] + pZ[1][row]) + (pZ[2][row] + pZ[3][row]);
    float a0 = 0.f, a1 = 0.f, a2 = 0.f, a3 = 0.f, ps = 0.f;
    const float* vbase = vb + (size_t)(b * SKVB) * DE + h * DH + d4;
    for (int e = 0; e < cnt; ++e) {
      const int kv = lkv[row][e];
      const float p = lpv[row][e];
      ps += p;
      const float4 vv = *(const float4*)(vbase + (size_t)kv * DE);
      a0 = fmaf(p, vv.x, a0); a1 = fmaf(p, vv.y, a1);
      a2 = fmaf(p, vv.z, a2); a3 = fmaf(p, vv.w, a3);
    }
    const float inv = 1.0f / (ps + 1e-8f * Zr);
    f16 o[4] = {(f16)(a0 * inv), (f16)(a1 * inv), (f16)(a2 * inv), (f16)(a3 * inv)};
    *(uint2*)(ob + (size_t)(b * SQB + qt * 16 + row) * DE + h * DH + d4) = *(const uint2*)o;
  }
}

// ---------------------------------------------------------------------------
extern "C" void kernel_launch(void* const* d_in, const int* in_sizes, int n_in,
                              void* d_out, int out_size, void* d_ws, size_t ws_size,
                              hipStream_t stream) {
  const float* x  = (const float*)d_in[0];
  const float* y  = (const float*)d_in[1];
  const float* wq = (const float*)d_in[2];
  const float* bq = (const float*)d_in[3];
  const float* wk = (const float*)d_in[4];
  const float* bk = (const float*)d_in[5];
  const float* wv = (const float*)d_in[6];
  const float* bv = (const float*)d_in[7];
  const float* wo = (const float*)d_in[8];
  const float* bo = (const float*)d_in[9];
  float* out = (float*)d_out;

  char* ws = (char*)d_ws;
  const size_t MiB = 1048576;

  f16* xh  = (f16*)(ws);                       // 16 MiB
  f16* xl  = (f16*)(ws + 16 * MiB);            // 16
  f16* yh  = (f16*)(ws + 32 * MiB);            // 12
  f16* yl  = (f16*)(ws + 44 * MiB);            // 12
  f16* qh  = (f16*)(ws + 56 * MiB);            // 16
  f16* ql  = (f16*)(ws + 72 * MiB);            // 16
  f16* kh  = (f16*)(ws + 88 * MiB);            // 8
  f16* kl  = (f16*)(ws + 96 * MiB);            // 8
  float* v = (float*)(ws + 104 * MiB);         // 16 (f32)
  f16* ao  = (f16*)(ws + 120 * MiB);           // 16
  f16* wqh = (f16*)(ws + 136 * MiB);
  f16* wql = (f16*)(ws + 136 * MiB + 524288);
  f16* wkh = (f16*)(ws + 137 * MiB);
  f16* wkl = (f16*)(ws + 137 * MiB + 786432);
  f16* wvh = (f16*)(ws + 138 * MiB + 524288);
  f16* wvl = (f16*)(ws + 139 * MiB + 262144);
  f16* woh = (f16*)(ws + 140 * MiB);
  f16* wol = (f16*)(ws + 140 * MiB + 524288);

  dim3 blk(256);
  const float WS = 2048.0f, IWS = 1.0f / 2048.0f;

  split_f16<<<dim3(8192), blk, 0, stream>>>(x, xh, xl, 2097152, 1.0f);
  split_f16<<<dim3(6144), blk, 0, stream>>>(y, yh, yl, 1572864, 1.0f);
  split_f16<<<dim3(256),  blk, 0, stream>>>(wq, wqh, wql, 65536, WS);
  split_f16<<<dim3(384),  blk, 0, stream>>>(wk, wkh, wkl, 98304, WS);
  split_f16<<<dim3(384),  blk, 0, stream>>>(wv, wvh, wvl, 98304, 1.0f);
  split_f16<<<dim3(256),  blk, 0, stream>>>(wo, woh, wol, 65536, 1.0f);

  // Q-proj -> split pair scaled x8  (q_true * 0.125 * 64)
  gemm_f16<3, 1><<<dim3(4, 128), blk, 0, stream>>>(xh, xl, wqh, wql, bq,
      nullptr, qh, ql, 16384, 512, 512, IWS, 8.0f);
  // K-proj -> split pair scaled x64
  gemm_f16<3, 1><<<dim3(4, 64), blk, 0, stream>>>(yh, yl, wkh, wkl, bk,
      nullptr, kh, kl, 8192, 512, 768, IWS, 64.0f);
  // V-proj -> f32
  gemm_f16<1, 0><<<dim3(4, 64), blk, 0, stream>>>(yh, nullptr, wvh, nullptr, bv,
      v, nullptr, nullptr, 8192, 512, 768, 1.0f, 1.0f);

  attn_v4<<<dim3(8192), blk, 0, stream>>>(qh, ql, kh, kl, v, ao);

  // O-proj
  gemm_f16<1, 0><<<dim3(4, 128), blk, 0, stream>>>(ao, nullptr, woh, nullptr, bo,
      out, nullptr, nullptr, 16384, 512, 512, 1.0f, 1.0f);
}

// Round 6
// 385.661 us; speedup vs baseline: 5.5970x; 1.0098x over previous
//
#include <hip/hip_runtime.h>
#include <cstdint>
#include <cmath>

#define DH 64
#define SQB 2048
#define SKVB 1024
#define DE 512

typedef _Float16 f16;
typedef _Float16 f16x8 __attribute__((ext_vector_type(8)));
typedef float f32x4 __attribute__((ext_vector_type(4)));

// ---------------------------------------------------------------------------
// Split fp32 -> (hi, lo) fp16 pair, optional pre-scale.
// ---------------------------------------------------------------------------
__global__ __launch_bounds__(256)
void split_f16(const float* __restrict__ in, f16* __restrict__ hi,
               f16* __restrict__ lo, int n4, float scale) {
  const int i = blockIdx.x * 256 + threadIdx.x;
  if (i >= n4) return;
  float4 v = ((const float4*)in)[i];
  v.x *= scale; v.y *= scale; v.z *= scale; v.w *= scale;
  f16 h0 = (f16)v.x, h1 = (f16)v.y, h2 = (f16)v.z, h3 = (f16)v.w;
  f16 l0 = (f16)(v.x - (float)h0), l1 = (f16)(v.y - (float)h1);
  f16 l2 = (f16)(v.z - (float)h2), l3 = (f16)(v.w - (float)h3);
  f16 hb[4] = {h0, h1, h2, h3};
  f16 lb[4] = {l0, l1, l2, l3};
  ((uint2*)hi)[i] = *(const uint2*)hb;
  ((uint2*)lo)[i] = *(const uint2*)lb;
}

// ---------------------------------------------------------------------------
// MFMA f16 GEMM (validated R4/R5 core). OUT=0: C fp32. OUT=1: split-f16 pair.
// ---------------------------------------------------------------------------
template <int NSPLIT, int OUT>
__global__ __launch_bounds__(256, 2)
void gemm_f16(const f16* __restrict__ Ah, const f16* __restrict__ Al,
              const f16* __restrict__ Wh, const f16* __restrict__ Wl,
              const float* __restrict__ bias, float* __restrict__ C,
              f16* __restrict__ Ch, f16* __restrict__ Cl,
              int M, int N, int K, float inv, float oscale) {
  __shared__ f16 smem[(NSPLIT == 3 ? 4 : 2) * 4096];
  f16* As  = smem;
  f16* Als = (NSPLIT == 3) ? smem + 4096 : nullptr;
  f16* Ws  = smem + (NSPLIT == 3 ? 8192 : 4096);
  f16* Wls = (NSPLIT == 3) ? smem + 12288 : nullptr;

  const int tid = threadIdx.x;
  const int w = tid >> 6;
  const int l = tid & 63;
  const int wm = w >> 1, wn = w & 1;
  const int m0 = blockIdx.y * 128;
  const int n0 = blockIdx.x * 128;

  const int srow = tid >> 2;
  const int schk = tid & 3;
  const f16* pA  = Ah + (size_t)(m0 + srow) * K + schk * 8;
  const f16* pW  = Wh + (size_t)(n0 + srow) * K + schk * 8;
  const f16* pAl = (NSPLIT == 3) ? Al + (size_t)(m0 + srow) * K + schk * 8 : nullptr;
  const f16* pWl = (NSPLIT == 3) ? Wl + (size_t)(n0 + srow) * K + schk * 8 : nullptr;
  const size_t rowskip = (size_t)64 * K;

  const int d0 = srow * 32 + ((schk ^ (srow & 3)) * 8);
  const int fbase = (l & 15) * 32 + (((l >> 4) ^ (l & 3)) * 8);
  const int fA = wm * 2048 + fbase;
  const int fW = wn * 2048 + fbase;

  f32x4 acc[4][4] = {};
  uint4 rA0, rA1, rW0, rW1, rAl0, rAl1, rWl0, rWl1;

  rA0 = *(const uint4*)(pA);            rA1 = *(const uint4*)(pA + rowskip);
  rW0 = *(const uint4*)(pW);            rW1 = *(const uint4*)(pW + rowskip);
  if constexpr (NSPLIT == 3) {
    rAl0 = *(const uint4*)(pAl);        rAl1 = *(const uint4*)(pAl + rowskip);
    rWl0 = *(const uint4*)(pWl);        rWl1 = *(const uint4*)(pWl + rowskip);
  }

  for (int k0 = 0; k0 < K; k0 += 32) {
    __syncthreads();
    *(uint4*)&As[d0] = rA0;  *(uint4*)&As[d0 + 2048] = rA1;
    *(uint4*)&Ws[d0] = rW0;  *(uint4*)&Ws[d0 + 2048] = rW1;
    if constexpr (NSPLIT == 3) {
      *(uint4*)&Als[d0] = rAl0;  *(uint4*)&Als[d0 + 2048] = rAl1;
      *(uint4*)&Wls[d0] = rWl0;  *(uint4*)&Wls[d0 + 2048] = rWl1;
    }
    __syncthreads();

    if (k0 + 32 < K) {
      rA0 = *(const uint4*)(pA + k0 + 32);  rA1 = *(const uint4*)(pA + rowskip + k0 + 32);
      rW0 = *(const uint4*)(pW + k0 + 32);  rW1 = *(const uint4*)(pW + rowskip + k0 + 32);
      if constexpr (NSPLIT == 3) {
        rAl0 = *(const uint4*)(pAl + k0 + 32); rAl1 = *(const uint4*)(pAl + rowskip + k0 + 32);
        rWl0 = *(const uint4*)(pWl + k0 + 32); rWl1 = *(const uint4*)(pWl + rowskip + k0 + 32);
      }
    }

    f16x8 ah[4], wh[4], al[4], wl[4];
#pragma unroll
    for (int i = 0; i < 4; ++i) ah[i] = *(const f16x8*)&As[fA + i * 512];
#pragma unroll
    for (int j = 0; j < 4; ++j) wh[j] = *(const f16x8*)&Ws[fW + j * 512];
    if constexpr (NSPLIT == 3) {
#pragma unroll
      for (int i = 0; i < 4; ++i) al[i] = *(const f16x8*)&Als[fA + i * 512];
#pragma unroll
      for (int j = 0; j < 4; ++j) wl[j] = *(const f16x8*)&Wls[fW + j * 512];
    }

#pragma unroll
    for (int i = 0; i < 4; ++i)
#pragma unroll
      for (int j = 0; j < 4; ++j)
        acc[i][j] = __builtin_amdgcn_mfma_f32_16x16x32_f16(ah[i], wh[j], acc[i][j], 0, 0, 0);
    if constexpr (NSPLIT == 3) {
#pragma unroll
      for (int i = 0; i < 4; ++i)
#pragma unroll
        for (int j = 0; j < 4; ++j)
          acc[i][j] = __builtin_amdgcn_mfma_f32_16x16x32_f16(ah[i], wl[j], acc[i][j], 0, 0, 0);
#pragma unroll
      for (int i = 0; i < 4; ++i)
#pragma unroll
        for (int j = 0; j < 4; ++j)
          acc[i][j] = __builtin_amdgcn_mfma_f32_16x16x32_f16(al[i], wh[j], acc[i][j], 0, 0, 0);
    }
  }

  const int rr = (l >> 4) * 4;
  const int cc = l & 15;
#pragma unroll
  for (int j = 0; j < 4; ++j) {
    const int n = n0 + wn * 64 + j * 16 + cc;
    const float bv = bias[n];
#pragma unroll
    for (int i = 0; i < 4; ++i) {
      const int m = m0 + wm * 64 + i * 16 + rr;
#pragma unroll
      for (int r = 0; r < 4; ++r) {
        const float val = acc[i][j][r] * inv + bv;
        if constexpr (OUT == 0) {
          C[(size_t)(m + r) * N + n] = val;
        } else {
          const float sv = val * oscale;
          const f16 hh = (f16)sv;
          const f16 ll = (f16)(sv - (float)hh);
          Ch[(size_t)(m + r) * N + n] = hh;
          Cl[(size_t)(m + r) * N + n] = ll;
        }
      }
    }
  }
}

// ---------------------------------------------------------------------------
// Fused sparse attention v5: MFMA QK^T (split-3 f16), lane owns q-row l&15,
// wave owns kv quarter. Phase-fused machinery: counts folded into the exp
// pass -> 4 barriers on the fast path (vs 7 in v4).
// S[t][r] = s_raw[q=l&15][kv = w*256 + t*16 + (l>>4)*4 + r], s_raw=4096*s.
// ---------------------------------------------------------------------------
__global__ __launch_bounds__(256, 4)
void attn_v5(const f16* __restrict__ qhb, const f16* __restrict__ qlb,
             const f16* __restrict__ khb, const f16* __restrict__ klb,
             const float* __restrict__ vb, f16* __restrict__ ob) {
  __shared__ float pM[4][16], pZ[4][16], pH[4][16], pC[4][16];
  __shared__ int cnt16[256];          // [group w*4+g][row] == [tid]
  __shared__ int lkv[16][40];
  __shared__ float lpv[16][40];
  __shared__ int lcnt[16];

  const int phys = blockIdx.x;
  const int bid = (phys & 7) * 1024 + (phys >> 3);   // XCD-pinned, bijective
  const int qt = bid & 127;
  const int h  = (bid >> 7) & 7;
  const int b  = bid >> 10;
  const int tid = threadIdx.x;
  const int w = tid >> 6;
  const int l = tid & 63;
  const int q16 = l & 15;
  const int g = l >> 4;

  // ---- Q fragments (B operand)
  const size_t qoff = (size_t)(b * SQB + qt * 16 + q16) * DE + h * DH + g * 8;
  const f16x8 qf_h0 = *(const f16x8*)(qhb + qoff);
  const f16x8 qf_h1 = *(const f16x8*)(qhb + qoff + 32);
  const f16x8 qf_l0 = *(const f16x8*)(qlb + qoff);
  const f16x8 qf_l1 = *(const f16x8*)(qlb + qoff + 32);

  // ---- K pointers (A operand)
  const size_t koff = (size_t)(b * SKVB + w * 256 + q16) * DE + h * DH + g * 8;
  const f16* kp  = khb + koff;
  const f16* klp = klb + koff;

  f32x4 S[16];
#pragma unroll
  for (int i = 0; i < 16; ++i) S[i] = (f32x4){0.f, 0.f, 0.f, 0.f};

  f16x8 ka0 = *(const f16x8*)(kp);
  f16x8 ka1 = *(const f16x8*)(kp + 32);
  f16x8 kb0 = *(const f16x8*)(klp);
  f16x8 kb1 = *(const f16x8*)(klp + 32);
#pragma unroll
  for (int t = 0; t < 16; ++t) {
    f16x8 na0, na1, nb0, nb1;
    if (t < 15) {
      na0 = *(const f16x8*)(kp + 8192);
      na1 = *(const f16x8*)(kp + 8192 + 32);
      nb0 = *(const f16x8*)(klp + 8192);
      nb1 = *(const f16x8*)(klp + 8192 + 32);
      kp += 8192; klp += 8192;
    }
    __builtin_amdgcn_s_setprio(1);
    S[t] = __builtin_amdgcn_mfma_f32_16x16x32_f16(ka0, qf_h0, S[t], 0, 0, 0);
    S[t] = __builtin_amdgcn_mfma_f32_16x16x32_f16(ka0, qf_l0, S[t], 0, 0, 0);
    S[t] = __builtin_amdgcn_mfma_f32_16x16x32_f16(kb0, qf_h0, S[t], 0, 0, 0);
    S[t] = __builtin_amdgcn_mfma_f32_16x16x32_f16(ka1, qf_h1, S[t], 0, 0, 0);
    S[t] = __builtin_amdgcn_mfma_f32_16x16x32_f16(ka1, qf_l1, S[t], 0, 0, 0);
    S[t] = __builtin_amdgcn_mfma_f32_16x16x32_f16(kb1, qf_h1, S[t], 0, 0, 0);
    __builtin_amdgcn_s_setprio(0);
    if (t < 15) { ka0 = na0; ka1 = na1; kb0 = nb0; kb1 = nb1; }
  }

  // ---- Phase 1: row max
  float mx = -INFINITY;
#pragma unroll
  for (int t = 0; t < 16; ++t)
#pragma unroll
    for (int r = 0; r < 4; ++r) mx = fmaxf(mx, S[t][r]);
  mx = fmaxf(mx, __shfl_xor(mx, 16));
  mx = fmaxf(mx, __shfl_xor(mx, 32));
  if (g == 0) pM[w][q16] = mx;
  __syncthreads();
  const float m = fmaxf(fmaxf(pM[0][q16], pM[1][q16]), fmaxf(pM[2][q16], pM[3][q16]));

  // ---- Phase 2 (fused): p = exp2(sv*C2); Z; H; count(p==1.0) per-lane + row
  const float C2 = 1.44269504f / 4096.0f;
  float Zl = 0.f, Hl = 0.f;
  int cl = 0;
#pragma unroll
  for (int t = 0; t < 16; ++t)
#pragma unroll
    for (int r = 0; r < 4; ++r) {
      const float sv = S[t][r] - m;
      const float p = __builtin_amdgcn_exp2f(sv * C2);
      S[t][r] = p;
      Zl += p;
      Hl = fmaf(p, sv, Hl);
      cl += (p == 1.0f) ? 1 : 0;
    }
  cnt16[tid] = cl;                       // per-lane selected count (fast path)
  float clf = (float)cl;
  Zl += __shfl_xor(Zl, 16); Zl += __shfl_xor(Zl, 32);
  Hl += __shfl_xor(Hl, 16); Hl += __shfl_xor(Hl, 32);
  clf += __shfl_xor(clf, 16); clf += __shfl_xor(clf, 32);
  if (g == 0) { pZ[w][q16] = Zl; pH[w][q16] = Hl; pC[w][q16] = clf; }
  __syncthreads();

  const float Z = (pZ[0][q16] + pZ[1][q16]) + (pZ[2][q16] + pZ[3][q16]);
  const float Hraw = (pH[0][q16] + pH[1][q16]) + (pH[2][q16] + pH[3][q16]);
  const float c1 = (pC[0][q16] + pC[1][q16]) + (pC[2][q16] + pC[3][q16]);
  const float E = __logf(Z) - (Hraw * (1.0f / 4096.0f)) / Z;
  int tk = (int)(32.0f * (1.0f - E));
  tk = tk < 1 ? 1 : (tk > 32 ? 32 : tk);

  float thr = 1.0f, cur = 1.0f, rem = (float)tk;
  bool pend = !(c1 >= rem);
  const bool rowSlow = pend;
  if (pend) rem -= c1;

  // ---- slow path (rare; row-pend pattern identical across waves -> uniform)
  unsigned long long bal = __ballot(pend);
  if (bal != 0ull) {
    int pass = 0;
    while (bal != 0ull && pass < 40) {
      ++pass;
      float lmx = -INFINITY;
#pragma unroll
      for (int t = 0; t < 16; ++t)
#pragma unroll
        for (int r = 0; r < 4; ++r) {
          const float p = S[t][r];
          lmx = (p < cur) ? fmaxf(lmx, p) : lmx;
        }
      lmx = fmaxf(lmx, __shfl_xor(lmx, 16));
      lmx = fmaxf(lmx, __shfl_xor(lmx, 32));
      if (g == 0) pM[w][q16] = lmx;
      __syncthreads();
      const float cand = fmaxf(fmaxf(pM[0][q16], pM[1][q16]), fmaxf(pM[2][q16], pM[3][q16]));
      float cf = 0.f;
#pragma unroll
      for (int t = 0; t < 16; ++t)
#pragma unroll
        for (int r = 0; r < 4; ++r) cf += (S[t][r] == cand) ? 1.f : 0.f;
      cf += __shfl_xor(cf, 16); cf += __shfl_xor(cf, 32);
      if (g == 0) pC[w][q16] = cf;
      __syncthreads();
      const float c2 = (pC[0][q16] + pC[1][q16]) + (pC[2][q16] + pC[3][q16]);
      if (pend) {
        if (c2 >= rem) { thr = cand; pend = false; }
        else { rem -= c2; cur = cand; }
      }
      bal = __ballot(pend);
    }
    // rebuild per-lane counts for slow rows
    if (rowSlow) {
      int ns = 0;
#pragma unroll
      for (int t = 0; t < 16; ++t)
#pragma unroll
        for (int r = 0; r < 4; ++r) ns += (S[t][r] >= thr) ? 1 : 0;
      cnt16[tid] = ns;
    }
    __syncthreads();
  }

  // ---- append selected (kv, p) per row; prefix over earlier lane-groups
  {
    int off = 0;
    const int me = w * 4 + g;
#pragma unroll
    for (int gi = 0; gi < 15; ++gi)
      if (gi < me) off += cnt16[gi * 16 + q16];
    int nsel = cnt16[me * 16 + q16];
    if (me == 15) lcnt[q16] = off + nsel;
#pragma unroll
    for (int t = 0; t < 16; ++t)
#pragma unroll
      for (int r = 0; r < 4; ++r) {
        if (S[t][r] >= thr) {
          if (off < 40) {
            lkv[q16][off] = w * 256 + t * 16 + g * 4 + r;
            lpv[q16][off] = S[t][r];
          }
          ++off;
        }
      }
  }
  __syncthreads();

  // ---- PV: row = tid>>4, d-chunk = (tid&15)*4
  {
    const int row = tid >> 4;
    const int d4 = (tid & 15) * 4;
    int cnt = lcnt[row]; cnt = cnt > 40 ? 40 : cnt;
    const float Zr = (pZ[0][row] + pZ[1][row]) + (pZ[2][row] + pZ[3][row]);
    float a0 = 0.f, a1 = 0.f, a2 = 0.f, a3 = 0.f, ps = 0.f;
    const float* vbase = vb + (size_t)(b * SKVB) * DE + h * DH + d4;
    for (int e = 0; e < cnt; ++e) {
      const int kv = lkv[row][e];
      const float p = lpv[row][e];
      ps += p;
      const float4 vv = *(const float4*)(vbase + (size_t)kv * DE);
      a0 = fmaf(p, vv.x, a0); a1 = fmaf(p, vv.y, a1);
      a2 = fmaf(p, vv.z, a2); a3 = fmaf(p, vv.w, a3);
    }
    const float inv = 1.0f / (ps + 1e-8f * Zr);
    f16 o[4] = {(f16)(a0 * inv), (f16)(a1 * inv), (f16)(a2 * inv), (f16)(a3 * inv)};
    *(uint2*)(ob + (size_t)(b * SQB + qt * 16 + row) * DE + h * DH + d4) = *(const uint2*)o;
  }
}

// ---------------------------------------------------------------------------
extern "C" void kernel_launch(void* const* d_in, const int* in_sizes, int n_in,
                              void* d_out, int out_size, void* d_ws, size_t ws_size,
                              hipStream_t stream) {
  const float* x  = (const float*)d_in[0];
  const float* y  = (const float*)d_in[1];
  const float* wq = (const float*)d_in[2];
  const float* bq = (const float*)d_in[3];
  const float* wk = (const float*)d_in[4];
  const float* bk = (const float*)d_in[5];
  const float* wv = (const float*)d_in[6];
  const float* bv = (const float*)d_in[7];
  const float* wo = (const float*)d_in[8];
  const float* bo = (const float*)d_in[9];
  float* out = (float*)d_out;

  char* ws = (char*)d_ws;
  const size_t MiB = 1048576;

  f16* xh  = (f16*)(ws);                       // 16 MiB
  f16* xl  = (f16*)(ws + 16 * MiB);            // 16
  f16* yh  = (f16*)(ws + 32 * MiB);            // 12
  f16* yl  = (f16*)(ws + 44 * MiB);            // 12
  f16* qh  = (f16*)(ws + 56 * MiB);            // 16
  f16* ql  = (f16*)(ws + 72 * MiB);            // 16
  f16* kh  = (f16*)(ws + 88 * MiB);            // 8
  f16* kl  = (f16*)(ws + 96 * MiB);            // 8
  float* v = (float*)(ws + 104 * MiB);         // 16 (f32)
  f16* ao  = (f16*)(ws + 120 * MiB);           // 16
  f16* wqh = (f16*)(ws + 136 * MiB);
  f16* wql = (f16*)(ws + 136 * MiB + 524288);
  f16* wkh = (f16*)(ws + 137 * MiB);
  f16* wkl = (f16*)(ws + 137 * MiB + 786432);
  f16* wvh = (f16*)(ws + 138 * MiB + 524288);
  f16* wvl = (f16*)(ws + 139 * MiB + 262144);
  f16* woh = (f16*)(ws + 140 * MiB);
  f16* wol = (f16*)(ws + 140 * MiB + 524288);

  dim3 blk(256);
  const float WS = 2048.0f, IWS = 1.0f / 2048.0f;

  split_f16<<<dim3(8192), blk, 0, stream>>>(x, xh, xl, 2097152, 1.0f);
  split_f16<<<dim3(6144), blk, 0, stream>>>(y, yh, yl, 1572864, 1.0f);
  split_f16<<<dim3(256),  blk, 0, stream>>>(wq, wqh, wql, 65536, WS);
  split_f16<<<dim3(384),  blk, 0, stream>>>(wk, wkh, wkl, 98304, WS);
  split_f16<<<dim3(384),  blk, 0, stream>>>(wv, wvh, wvl, 98304, 1.0f);
  split_f16<<<dim3(256),  blk, 0, stream>>>(wo, woh, wol, 65536, 1.0f);

  // Q-proj -> split pair scaled x8  (q_true * 0.125 * 64)
  gemm_f16<3, 1><<<dim3(4, 128), blk, 0, stream>>>(xh, xl, wqh, wql, bq,
      nullptr, qh, ql, 16384, 512, 512, IWS, 8.0f);
  // K-proj -> split pair scaled x64
  gemm_f16<3, 1><<<dim3(4, 64), blk, 0, stream>>>(yh, yl, wkh, wkl, bk,
      nullptr, kh, kl, 8192, 512, 768, IWS, 64.0f);
  // V-proj -> f32
  gemm_f16<1, 0><<<dim3(4, 64), blk, 0, stream>>>(yh, nullptr, wvh, nullptr, bv,
      v, nullptr, nullptr, 8192, 512, 768, 1.0f, 1.0f);

  attn_v5<<<dim3(8192), blk, 0, stream>>>(qh, ql, kh, kl, v, ao);

  // O-proj
  gemm_f16<1, 0><<<dim3(4, 128), blk, 0, stream>>>(ao, nullptr, woh, nullptr, bo,
      out, nullptr, nullptr, 16384, 512, 512, 1.0f, 1.0f);
}